// Round 7
// baseline (417.144 us; speedup 1.0000x reference)
//
#include <hip/hip_runtime.h>
#include <hip/hip_bf16.h>

#define TWO_PI 6.28318530717958647692f

typedef __attribute__((ext_vector_type(8))) short bf16x8;
typedef __attribute__((ext_vector_type(4))) float f32x4;

__device__ __forceinline__ unsigned short f2bf(float v) {
    __hip_bfloat16 h = __float2bfloat16(v);
    return *(unsigned short*)&h;
}

__device__ __forceinline__ bf16x8 cvt8(float4 a, float4 b) {
    bf16x8 r;
    r[0] = (short)f2bf(a.x); r[1] = (short)f2bf(a.y);
    r[2] = (short)f2bf(a.z); r[3] = (short)f2bf(a.w);
    r[4] = (short)f2bf(b.x); r[5] = (short)f2bf(b.y);
    r[6] = (short)f2bf(b.z); r[7] = (short)f2bf(b.w);
    return r;
}

// Problem: B=32, M=N=128, I=O=64, NM=16.
// Spectral path keeps only km in {0..15, 112..127} (p=0..31) and kn=0..15 (q).
// Spectral branch contributes ~1e-6 abs to y -> bf16/rotator-drift there is free.
//
// R5 lesson: MFMA operands from global serialize when loaded per-MFMA.
// R7: W2 frags ARE from global but hoisted as one 16-load batch per head,
// L2-hot, with 3 blocks/CU to hide — structurally m97-like, not R5-like.
//
// ws layout (float offsets):
//   w0t     @ 0        : 262144   (32 p x 64 i x 64 j complex)
//   w1t     @ 262144   : 262144   (2 h x 16 kv x 64 j x 64 o complex)
//   T       @ 524288   : 8388608  ([b][u][q][o] complex)
//   A       @ 8912896  : 8388608  ([b][m][kv][i] complex)  (dead after k2)
//   xft     @ 17301504 : 2097152  (dead after k3a)
//   c1      @ 19398656 : 2097152  (dead after k3b)
//   oft     @ 21495808 : 2097152  (dead after k4)
//   w1bt    @ 23592960 : 16384 u16  W1t[2][o:128][k:64] bf16 PRE-SWIZZLED
//   w2bt    @ 23601152 : 16384 u16  W2t[2][o:64][k:128] bf16 linear (reg loads)
//   wlt_pre @ 23609344 : 4096 u16   w_lin^T [o:64][k:64] bf16 pre-swizzled
//   ctb_pre @ 23611392 : 4096 u16   irfft coeff [v:128][k:32] bf16 pre-swizzled

__global__ __launch_bounds__(256) void k0_prep(const float* __restrict__ ws0,
                                               const float* __restrict__ ws1,
                                               float2* __restrict__ w0t,
                                               float2* __restrict__ w1t)
{
    int tgt = blockIdx.x * 256 + threadIdx.x;   // 0..262143
    if (tgt < 131072) {
        int p = tgt >> 12;
        int rem = tgt & 4095;
        int i = rem >> 6, j = rem & 63;
        const float* s = (p < 16) ? ws0 : ws1;   // f=0 plane
        int px = p & 15;
        int base = ((i * 64 + j) * 16 + px) * 2;
        w0t[tgt] = make_float2(s[base], s[base + 1]);
    } else {
        int u = tgt - 131072;
        int h = u >> 16;
        int kv = (u >> 12) & 15;
        int j = (u >> 6) & 63;
        int o = u & 63;
        const float* s = (h ? ws1 : ws0) + 131072;  // f=1 plane
        int base = ((j * 64 + o) * 16 + kv) * 2;
        w1t[u] = make_float2(s[base], s[base + 1]);
    }
}

// head weights bf16 + w_lin^T + irfft coefficient matrix (all pre-swizzled
// where consumed from LDS; w2bt linear for register loads)
__global__ __launch_bounds__(256) void k0b_prep(const float* __restrict__ wb1,
                                                const float* __restrict__ wf1,
                                                const float* __restrict__ wb2,
                                                const float* __restrict__ wf2,
                                                const float* __restrict__ wl,
                                                unsigned short* __restrict__ w1bt,
                                                unsigned short* __restrict__ w2bt,
                                                unsigned short* __restrict__ wlt_pre,
                                                unsigned short* __restrict__ ctb_pre)
{
    int tgt = blockIdx.x * 256 + threadIdx.x;   // 0..40959
    if (tgt < 16384) {
        int head = tgt >> 13;
        int o = (tgt >> 6) & 127;
        int i = tgt & 63;
        const float* src = head ? wf1 : wb1;    // [64][128]
        // pre-swizzle: chunk ch=i>>3 lands at ch^(o&7)
        int dst = head * 8192 + o * 64 + (((i >> 3) ^ (o & 7)) << 3) + (i & 7);
        w1bt[dst] = f2bf(src[i * 128 + o]);
    } else if (tgt < 32768) {
        int u = tgt - 16384;
        int head = u >> 13;
        int o = (u >> 7) & 63;
        int c = u & 127;
        const float* src = head ? wf2 : wb2;    // [128][64]
        w2bt[u] = f2bf(src[c * 64 + o]);        // linear [head][o][k]
    } else if (tgt < 36864) {
        int u = tgt - 32768;                    // 0..4095
        int o = u >> 6, i = u & 63;
        int chunk = (i >> 3) ^ (o & 7);
        wlt_pre[o * 64 + chunk * 8 + (i & 7)] = f2bf(wl[i * 64 + o]);
    } else {
        int u = tgt - 36864;                    // 0..4095
        int v = u >> 5, k = u & 31;             // v 0..127, k 0..31
        float val;
        if (k < 16) {
            val = (k == 0) ? (1.0f / 128.0f)
                           : (2.0f / 128.0f) * cosf(TWO_PI * k * v * (1.0f / 128.0f));
        } else {
            int q = k - 16;
            val = (q == 0) ? 0.f
                           : -(2.0f / 128.0f) * sinf(TWO_PI * q * v * (1.0f / 128.0f));
        }
        int chunk = (k >> 3) ^ ((v >> 1) & 3);
        ctb_pre[v * 32 + chunk * 8 + (k & 7)] = f2bf(val);
    }
}

// k1 v2: A[b,m,kv,i] = sum_n x[b,m,n,i] e^{-2pi i kv n/128}, kv=0..15.
// Twiddles via in-register rotator recurrence (no LDS table reads).
// Thread = 2 i x 2 kv. Inner step: 1 ds_read_b64 + 16 VALU ops.
__global__ __launch_bounds__(256) void k1_dft_n(const float* __restrict__ x,
                                                float2* __restrict__ A)
{
    __shared__ float Xs[128][64];
    const int t = threadIdx.x;
    const int bm = blockIdx.x;
    const float4* xg4 = (const float4*)(x + (size_t)bm * 8192);
    float4* Xs4 = (float4*)&Xs[0][0];
    for (int k = t; k < 2048; k += 256) Xs4[k] = xg4[k];
    __syncthreads();
    const int ip = (t & 31) << 1;     // i pair
    const int kv0 = (t >> 5) << 1;    // 2 kv
    float wr[2] = {1.f, 1.f}, wi[2] = {0.f, 0.f};
    float cr[2], sr[2];
    #pragma unroll
    for (int j = 0; j < 2; ++j) {
        float th = (float)(kv0 + j) * (TWO_PI / 128.0f);
        cr[j] = cosf(th); sr[j] = sinf(th);
    }
    float re[2][2] = {{0.f,0.f},{0.f,0.f}}, im[2][2] = {{0.f,0.f},{0.f,0.f}};
    for (int n = 0; n < 128; ++n) {
        float2 v = *(const float2*)&Xs[n][ip];
        #pragma unroll
        for (int j = 0; j < 2; ++j) {
            re[j][0] += v.x * wr[j];  im[j][0] -= v.x * wi[j];
            re[j][1] += v.y * wr[j];  im[j][1] -= v.y * wi[j];
            float nwr = wr[j] * cr[j] - wi[j] * sr[j];
            float nwi = wr[j] * sr[j] + wi[j] * cr[j];
            wr[j] = nwr; wi[j] = nwi;
        }
    }
    float4* Ap = (float4*)(A + (size_t)bm * 1024);
    #pragma unroll
    for (int j = 0; j < 2; ++j)
        Ap[((kv0 + j) * 64 + ip) >> 1] =
            make_float4(re[j][0], im[j][0], re[j][1], im[j][1]);
}

// k2 v2: xft[b,p,kv,i] = (1/128) sum_m A[b,m,kv,i] e^{-2pi i km(p) m/128}.
// Rotator recurrence per p (8 p/thread); As packed bf16 pair (33KB LDS).
__global__ __launch_bounds__(256) void k2_dft_m(const float2* __restrict__ A,
                                                float2* __restrict__ xft)
{
    __shared__ unsigned int As[128][64];   // bf16(re) | bf16(im)<<16
    const int t = threadIdx.x;
    const int b = blockIdx.x >> 4, kv = blockIdx.x & 15;
    for (int k = t; k < 8192; k += 256) {
        int m = k >> 6, i = k & 63;
        float2 a = A[((size_t)(b * 128 + m) * 16 + kv) * 64 + i];
        As[m][i] = (unsigned)f2bf(a.x) | ((unsigned)f2bf(a.y) << 16);
    }
    __syncthreads();
    const int i = t & 63;
    const int p0 = (t >> 6) << 3;
    float wr[8], wi[8], cr[8], sr[8];
    float2 acc[8];
    #pragma unroll
    for (int j = 0; j < 8; ++j) {
        int p = p0 + j;
        int km = (p < 16) ? p : (96 + p);
        float th = (float)km * (TWO_PI / 128.0f);
        cr[j] = cosf(th); sr[j] = sinf(th);
        wr[j] = 1.f; wi[j] = 0.f;
        acc[j] = make_float2(0.f, 0.f);
    }
    for (int m = 0; m < 128; ++m) {
        unsigned pk = As[m][i];
        float ax = __uint_as_float(pk << 16);
        float ay = __uint_as_float(pk & 0xffff0000u);
        #pragma unroll
        for (int j = 0; j < 8; ++j) {
            acc[j].x += ax * wr[j] + ay * wi[j];   // a * e^{-i th}
            acc[j].y += ay * wr[j] - ax * wi[j];
            float nwr = wr[j] * cr[j] - wi[j] * sr[j];
            float nwi = wr[j] * sr[j] + wi[j] * cr[j];
            wr[j] = nwr; wi[j] = nwi;
        }
    }
    const float sc = 1.0f / 128.0f;
    #pragma unroll
    for (int j = 0; j < 8; ++j)
        xft[((size_t)(b * 32 + p0 + j) * 16 + kv) * 64 + i] =
            make_float2(acc[j].x * sc, acc[j].y * sc);
}

// k3a: c1[b,p,kv,j] = sum_i xft[b,p,kv,i] * w0c[i,j,p]
__global__ __launch_bounds__(256) void k3a_spec1(const float2* __restrict__ xft,
                                                 const float2* __restrict__ w0t,
                                                 float2* __restrict__ c1)
{
    __shared__ __align__(16) float2 xs[16][64];
    __shared__ __align__(16) float2 w0s[64][64];
    const int t = threadIdx.x;
    const int b = blockIdx.x >> 5, p = blockIdx.x & 31;
    const float2* xg = xft + (size_t)(b * 32 + p) * 1024;
    for (int k = t; k < 1024; k += 256) ((float2*)xs)[k] = xg[k];
    const float4* wg = (const float4*)(w0t + (size_t)p * 4096);
    for (int k = t; k < 2048; k += 256) ((float4*)w0s)[k] = wg[k];
    __syncthreads();
    const int j = t & 63;
    const int kv0 = (t >> 6) << 2;
    float2 acc[4];
    #pragma unroll
    for (int q = 0; q < 4; ++q) acc[q] = make_float2(0.f, 0.f);
    for (int i = 0; i < 64; ++i) {
        float2 w = w0s[i][j];
        #pragma unroll
        for (int q = 0; q < 4; ++q) {
            float2 a = xs[kv0 + q][i];
            acc[q].x += a.x * w.x - a.y * w.y;
            acc[q].y += a.x * w.y + a.y * w.x;
        }
    }
    #pragma unroll
    for (int q = 0; q < 4; ++q)
        c1[((size_t)(b * 32 + p) * 16 + kv0 + q) * 64 + j] = acc[q];
}

// k3b: oft[b,p,kv,o] = sum_j c1[b,p,kv,j] * w1c[j,o,kv]  (weights per half h=p/16)
__global__ __launch_bounds__(256) void k3b_spec2(const float2* __restrict__ c1,
                                                 const float2* __restrict__ w1t,
                                                 float2* __restrict__ oft)
{
    __shared__ __align__(16) float2 cs[16][64];
    __shared__ __align__(16) float2 w1s[64][64];
    const int t = threadIdx.x;
    int id = blockIdx.x;
    const int h = id & 1; id >>= 1;
    const int kv = id & 15; const int b = id >> 4;
    for (int k = t; k < 1024; k += 256) {
        int pp = k >> 6, j = k & 63;
        cs[pp][j] = c1[((size_t)(b * 32 + h * 16 + pp) * 16 + kv) * 64 + j];
    }
    const float4* wg = (const float4*)(w1t + (size_t)(h * 16 + kv) * 4096);
    for (int k = t; k < 2048; k += 256) ((float4*)w1s)[k] = wg[k];
    __syncthreads();
    const int o = t & 63;
    const int pp0 = (t >> 6) << 2;
    float2 acc[4];
    #pragma unroll
    for (int q = 0; q < 4; ++q) acc[q] = make_float2(0.f, 0.f);
    for (int j = 0; j < 64; ++j) {
        float2 w = w1s[j][o];
        #pragma unroll
        for (int q = 0; q < 4; ++q) {
            float2 a = cs[pp0 + q][j];
            acc[q].x += a.x * w.x - a.y * w.y;
            acc[q].y += a.x * w.y + a.y * w.x;
        }
    }
    #pragma unroll
    for (int q = 0; q < 4; ++q)
        oft[((size_t)(b * 32 + h * 16 + pp0 + q) * 16 + kv) * 64 + o] = acc[q];
}

// k4: T[b,u,q,o] = sum_p oft[b,p,q,o] * exp(+2pi i km(p) u/128)
__global__ __launch_bounds__(256) void k4_idft_m(const float2* __restrict__ oft,
                                                 float2* __restrict__ T)
{
    __shared__ float2 Os[32][64];
    __shared__ __align__(8) float2 tcs[128];
    const int t = threadIdx.x;
    const int b = blockIdx.x >> 4, q = blockIdx.x & 15;
    if (t < 128) { float a = t * (TWO_PI / 128.0f); tcs[t] = make_float2(cosf(a), sinf(a)); }
    for (int k = t; k < 2048; k += 256) {
        int p = k >> 6, o = k & 63;
        Os[p][o] = oft[((size_t)(b * 32 + p) * 16 + q) * 64 + o];
    }
    __syncthreads();
    const int o = t & 63;
    const int u0 = (t >> 6) << 5;
    float2 op[32];
    #pragma unroll
    for (int p = 0; p < 32; ++p) op[p] = Os[p][o];
    for (int du = 0; du < 32; ++du) {
        int u = u0 + du;
        float ax = 0.f, ay = 0.f;
        #pragma unroll
        for (int p = 0; p < 32; ++p) {
            int km = (p < 16) ? p : (96 + p);
            int idx = (km * u) & 127;
            float2 cs = tcs[idx];
            ax += op[p].x * cs.x - op[p].y * cs.y;  // a * e^{+i th}
            ay += op[p].x * cs.y + op[p].y * cs.x;
        }
        T[((size_t)(b * 128 + u) * 16 + q) * 64 + o] = make_float2(ax, ay);
    }
}

// k56 v4: all-MFMA fused tail, 3 blocks/CU target.
// LDS 52K: S(20K: phase-A tables -> w1s 16K) + 4x8K wave-private (ys 4K | hs 4K).
// W2 in registers (one 16-frag batched load per head, L2-hot).
// 5 barriers/block.
__global__ __launch_bounds__(256) void k56_fused(
    const float* __restrict__ x, const float2* __restrict__ T,
    const float* __restrict__ bl,
    const unsigned short* __restrict__ ctb_pre, const unsigned short* __restrict__ wlt_pre,
    const unsigned short* __restrict__ w1bt, const unsigned short* __restrict__ w2bt,
    const float* __restrict__ bb1, const float* __restrict__ bb2,
    const float* __restrict__ bf1, const float* __restrict__ bf2,
    float* __restrict__ out)
{
    __shared__ __align__(16) unsigned char S[20480];
    __shared__ __align__(16) unsigned short priv[4][4096];

    unsigned short* Ctb = (unsigned short*)S;             // [v:128][k:32] 8K
    unsigned short* wlt = (unsigned short*)(S + 8192);    // [o:64][k:64]  8K
    unsigned short* Tpk = (unsigned short*)(S + 16384);   // [o:64][k:32]  4K
    unsigned short* w1s = (unsigned short*)S;             // [o:128][k:64] 16K (phase B)

    const int t = threadIdx.x;
    const int bm = blockIdx.x;
    const int lane = t & 63, wv = t >> 6;
    const int ar = lane & 15, kg = lane >> 4;
    const int R0 = wv * 32;
    unsigned short* ysw = priv[wv];          // [32][64] swizzled, wave-private
    unsigned short* hsw = priv[wv] + 2048;   // [16][128] swizzled, wave-private

    // ---- B1 stage: Ctb/wlt straight copies (pre-swizzled), Tpk pack ----
    {
        const uint4* cg = (const uint4*)ctb_pre;
        for (int k = t; k < 512; k += 256) ((uint4*)Ctb)[k] = cg[k];
        const uint4* wg = (const uint4*)wlt_pre;
        for (int k = t; k < 512; k += 256) ((uint4*)wlt)[k] = wg[k];
        const float2* Tg = T + (size_t)bm * 1024;
        for (int idx = t; idx < 1024; idx += 256) {
            int q = idx >> 6, o = idx & 63;
            float2 v = Tg[idx];
            int f = (o >> 1) & 3;
            Tpk[o * 32 + (((q >> 3) ^ f) << 3) + (q & 7)] = f2bf(v.x);
            Tpk[o * 32 + (((2 + (q >> 3)) ^ f) << 3) + (q & 7)] = f2bf(v.y);
        }
    }
    __syncthreads();   // B1

    float biasl[4];
    #pragma unroll
    for (int ct = 0; ct < 4; ++ct) biasl[ct] = bl[ct * 16 + ar];

    // ---- phase A: y rows (wave-private) via MFMA ----
    #pragma unroll
    for (int rt = 0; rt < 2; ++rt) {
        const int vrow = R0 + rt * 16 + ar;
        const float* xr = x + (size_t)bm * 8192 + vrow * 64 + kg * 8;
        float4 xa0 = *(const float4*)(xr);
        float4 xa1 = *(const float4*)(xr + 4);
        float4 xb0 = *(const float4*)(xr + 32);
        float4 xb1 = *(const float4*)(xr + 36);
        bf16x8 a0 = cvt8(xa0, xa1);
        bf16x8 a1 = cvt8(xb0, xb1);
        bf16x8 asp = *(const bf16x8*)&Ctb[vrow * 32 + ((kg ^ ((vrow >> 1) & 3)) << 3)];
        f32x4 acc[4];
        #pragma unroll
        for (int ct = 0; ct < 4; ++ct) acc[ct] = (f32x4){0.f, 0.f, 0.f, 0.f};
        #pragma unroll
        for (int ct = 0; ct < 4; ++ct) {
            int o = ct * 16 + ar;
            bf16x8 b0 = *(const bf16x8*)&wlt[o * 64 + ((kg ^ (o & 7)) << 3)];
            bf16x8 b1 = *(const bf16x8*)&wlt[o * 64 + (((4 + kg) ^ (o & 7)) << 3)];
            bf16x8 bsp = *(const bf16x8*)&Tpk[o * 32 + ((kg ^ ((o >> 1) & 3)) << 3)];
            acc[ct] = __builtin_amdgcn_mfma_f32_16x16x32_bf16(a0, b0, acc[ct], 0, 0, 0);
            acc[ct] = __builtin_amdgcn_mfma_f32_16x16x32_bf16(a1, b1, acc[ct], 0, 0, 0);
            acc[ct] = __builtin_amdgcn_mfma_f32_16x16x32_bf16(asp, bsp, acc[ct], 0, 0, 0);
        }
        #pragma unroll
        for (int ct = 0; ct < 4; ++ct) {
            int col = ct * 16 + ar;
            #pragma unroll
            for (int r = 0; r < 4; ++r) {
                int rl = rt * 16 + kg * 4 + r;   // wave-local row
                float v = fmaxf(acc[ct][r] + biasl[ct], 0.f);
                ysw[rl * 64 + (((col >> 3) ^ (rl & 7)) << 3) + (col & 7)] = f2bf(v);
            }
        }
    }
    __syncthreads();   // B2: table reads done -> S reusable for w1s

    // ---- phase B: heads ----
    for (int head = 0; head < 2; ++head) {
        // stage w1s (straight uint4 copy; w1bt pre-swizzled)
        {
            const uint4* g1 = (const uint4*)(w1bt + head * 8192);
            for (int k = t; k < 1024; k += 256) ((uint4*)w1s)[k] = g1[k];
        }
        // W2 fragments -> registers (batched, L2-hot)
        bf16x8 w2f[4][4];
        #pragma unroll
        for (int ks = 0; ks < 4; ++ks)
            #pragma unroll
            for (int ct = 0; ct < 4; ++ct)
                w2f[ks][ct] = *(const bf16x8*)&w2bt[head * 8192 +
                                (ct * 16 + ar) * 128 + ks * 32 + kg * 8];
        const float* B1 = head ? bf1 : bb1;
        const float* B2 = head ? bf2 : bb2;
        float bias1[8], bias2[4];
        #pragma unroll
        for (int c = 0; c < 8; ++c) bias1[c] = B1[c * 16 + ar];
        #pragma unroll
        for (int c = 0; c < 4; ++c) bias2[c] = B2[c * 16 + ar];
        __syncthreads();   // B3/B5: w1s visible

        #pragma unroll
        for (int rt = 0; rt < 2; ++rt) {
            // GEMM1: 16x128, K=64. A from ysw (wave-local), B from w1s.
            const int yrl = rt * 16 + ar;
            bf16x8 ya0 = *(const bf16x8*)&ysw[yrl * 64 + ((kg ^ (yrl & 7)) << 3)];
            bf16x8 ya1 = *(const bf16x8*)&ysw[yrl * 64 + (((4 + kg) ^ (yrl & 7)) << 3)];
            f32x4 acc1[8];
            #pragma unroll
            for (int ct = 0; ct < 8; ++ct) acc1[ct] = (f32x4){0.f, 0.f, 0.f, 0.f};
            #pragma unroll
            for (int ct = 0; ct < 8; ++ct) {
                int brow = ct * 16 + ar;
                bf16x8 b0 = *(const bf16x8*)&w1s[brow * 64 + ((kg ^ (brow & 7)) << 3)];
                bf16x8 b1 = *(const bf16x8*)&w1s[brow * 64 + (((4 + kg) ^ (brow & 7)) << 3)];
                acc1[ct] = __builtin_amdgcn_mfma_f32_16x16x32_bf16(ya0, b0, acc1[ct], 0, 0, 0);
                acc1[ct] = __builtin_amdgcn_mfma_f32_16x16x32_bf16(ya1, b1, acc1[ct], 0, 0, 0);
            }
            // h -> wave-private LDS (swizzled), relu+bias
            #pragma unroll
            for (int ct = 0; ct < 8; ++ct) {
                #pragma unroll
                for (int r = 0; r < 4; ++r) {
                    int row = kg * 4 + r;          // 0..15 local
                    int col = ct * 16 + ar;
                    float v = fmaxf(acc1[ct][r] + bias1[ct], 0.f);
                    hsw[row * 128 + (((col >> 3) ^ (row & 7)) << 3) + (col & 7)] = f2bf(v);
                }
            }
            // GEMM2: 16x64, K=128. A from hsw, B from registers.
            f32x4 acc2[4];
            #pragma unroll
            for (int ct = 0; ct < 4; ++ct) acc2[ct] = (f32x4){0.f, 0.f, 0.f, 0.f};
            #pragma unroll
            for (int ks = 0; ks < 4; ++ks) {
                bf16x8 a = *(const bf16x8*)&hsw[ar * 128 + (((ks * 4 + kg) ^ (ar & 7)) << 3)];
                #pragma unroll
                for (int ct = 0; ct < 4; ++ct)
                    acc2[ct] = __builtin_amdgcn_mfma_f32_16x16x32_bf16(a, w2f[ks][ct], acc2[ct], 0, 0, 0);
            }
            float* og = out + (size_t)head * 33554432u + (size_t)bm * 8192;
            const int rowbase = R0 + rt * 16;
            #pragma unroll
            for (int ct = 0; ct < 4; ++ct) {
                #pragma unroll
                for (int r = 0; r < 4; ++r)
                    og[(size_t)(rowbase + kg * 4 + r) * 64 + ct * 16 + ar] =
                        acc2[ct][r] + bias2[ct];
            }
        }
        if (head == 0) __syncthreads();   // B4: w1s reads done before restage
    }
}

extern "C" void kernel_launch(void* const* d_in, const int* in_sizes, int n_in,
                              void* d_out, int out_size, void* d_ws, size_t ws_size,
                              hipStream_t stream)
{
    (void)in_sizes; (void)n_in; (void)out_size; (void)ws_size;
    const float* x   = (const float*)d_in[0];
    const float* ws0 = (const float*)d_in[1];
    const float* ws1 = (const float*)d_in[2];
    const float* wl  = (const float*)d_in[3];
    const float* bl  = (const float*)d_in[4];
    const float* wb1 = (const float*)d_in[5];
    const float* bb1 = (const float*)d_in[6];
    const float* wb2 = (const float*)d_in[7];
    const float* bb2 = (const float*)d_in[8];
    const float* wf1 = (const float*)d_in[9];
    const float* bf1 = (const float*)d_in[10];
    const float* wf2 = (const float*)d_in[11];
    const float* bf2 = (const float*)d_in[12];
    float* out = (float*)d_out;

    float* ws = (float*)d_ws;
    float2* w0t = (float2*)ws;                     // 131072 float2
    float2* w1t = (float2*)(ws + 262144);          // 131072 float2
    float2* Tb  = (float2*)(ws + 524288);          // 4194304 float2
    float2* Ab  = (float2*)(ws + 8912896);         // 4194304 float2 (dead after k2)
    float2* xft = (float2*)(ws + 17301504);        // 1048576 float2 (dead after k3a)
    float2* c1b = (float2*)(ws + 19398656);        // 1048576 float2 (dead after k3b)
    float2* oft = (float2*)(ws + 21495808);        // 1048576 float2 (dead after k4)
    unsigned short* w1bt    = (unsigned short*)(ws + 23592960);  // 16384 u16
    unsigned short* w2bt    = (unsigned short*)(ws + 23601152);  // 16384 u16
    unsigned short* wlt_pre = (unsigned short*)(ws + 23609344);  // 4096 u16
    unsigned short* ctb_pre = (unsigned short*)(ws + 23611392);  // 4096 u16

    k0_prep    <<<1024, 256, 0, stream>>>(ws0, ws1, w0t, w1t);
    k0b_prep   <<<160,  256, 0, stream>>>(wb1, wf1, wb2, wf2, wl,
                                          w1bt, w2bt, wlt_pre, ctb_pre);
    k1_dft_n   <<<4096, 256, 0, stream>>>(x, Ab);
    k2_dft_m   <<<512,  256, 0, stream>>>(Ab, xft);
    k3a_spec1  <<<1024, 256, 0, stream>>>(xft, w0t, c1b);
    k3b_spec2  <<<1024, 256, 0, stream>>>(c1b, w1t, oft);
    k4_idft_m  <<<512,  256, 0, stream>>>(oft, Tb);
    k56_fused  <<<4096, 256, 0, stream>>>(x, Tb, bl, ctb_pre, wlt_pre,
                                          w1bt, w2bt, bb1, bb2, bf1, bf2, out);
}

// Round 8
// 346.664 us; speedup vs baseline: 1.2033x; 1.2033x over previous
//
#include <hip/hip_runtime.h>
#include <hip/hip_bf16.h>

#define TWO_PI 6.28318530717958647692f

typedef __attribute__((ext_vector_type(8))) short bf16x8;
typedef __attribute__((ext_vector_type(4))) float f32x4;

__device__ __forceinline__ unsigned short f2bf(float v) {
    __hip_bfloat16 h = __float2bfloat16(v);
    return *(unsigned short*)&h;
}

__device__ __forceinline__ bf16x8 cvt8(float4 a, float4 b) {
    bf16x8 r;
    r[0] = (short)f2bf(a.x); r[1] = (short)f2bf(a.y);
    r[2] = (short)f2bf(a.z); r[3] = (short)f2bf(a.w);
    r[4] = (short)f2bf(b.x); r[5] = (short)f2bf(b.y);
    r[6] = (short)f2bf(b.z); r[7] = (short)f2bf(b.w);
    return r;
}

// Problem: B=32, M=N=128, I=O=64, NM=16.
// Spectral path keeps km in {0..15,112..127} (p=0..31), kn=0..15 (q).
// Spectral branch contributes ~1e-6 abs to y -> bf16 anywhere in it is free.
// A and T are stored as packed bf16 pairs (u32: re low, im high) to halve HBM.
//
// R5 lesson: MFMA operands must come from LDS/regs (per-MFMA global loads stall).
// R7 lesson: W2-in-regs + per-head restage regressed; R6 structure restored.
//
// ws layout (float offsets):
//   w0t     @ 0        : 262144   (32 p x 64 i x 64 j complex fp32)
//   w1t     @ 262144   : 262144   (2 h x 16 kv x 64 j x 64 o complex fp32)
//   T       @ 524288   : 4194304 u32 packed bf16 (b,u,q,o)
//   A       @ 8912896  : 4194304 u32 packed bf16 (b,m,kv,i)  (dead after k2)
//   xft     @ 17301504 : 2097152 fp32 (dead after k3a)
//   c1      @ 19398656 : 2097152 fp32 (dead after k3b)
//   oft     @ 21495808 : 2097152 fp32 (dead after k4)
//   w1bt    @ 23592960 : 16384 u16  W1t[2][o:128][k:64] bf16 PRE-SWIZZLED
//   w2bt    @ 23601152 : 16384 u16  W2t[2][o:64][k:128] bf16 PRE-SWIZZLED
//   wlt_pre @ 23609344 : 4096 u16   w_lin^T [o:64][k:64] bf16 pre-swizzled
//   ctb_pre @ 23611392 : 4096 u16   irfft coeff [v:128][k:32] bf16 pre-swizzled

__global__ __launch_bounds__(256) void k0_prep(const float* __restrict__ ws0,
                                               const float* __restrict__ ws1,
                                               float2* __restrict__ w0t,
                                               float2* __restrict__ w1t)
{
    int tgt = blockIdx.x * 256 + threadIdx.x;   // 0..262143
    if (tgt < 131072) {
        int p = tgt >> 12;
        int rem = tgt & 4095;
        int i = rem >> 6, j = rem & 63;
        const float* s = (p < 16) ? ws0 : ws1;   // f=0 plane
        int px = p & 15;
        int base = ((i * 64 + j) * 16 + px) * 2;
        w0t[tgt] = make_float2(s[base], s[base + 1]);
    } else {
        int u = tgt - 131072;
        int h = u >> 16;
        int kv = (u >> 12) & 15;
        int j = (u >> 6) & 63;
        int o = u & 63;
        const float* s = (h ? ws1 : ws0) + 131072;  // f=1 plane
        int base = ((j * 64 + o) * 16 + kv) * 2;
        w1t[u] = make_float2(s[base], s[base + 1]);
    }
}

// head weights bf16 pre-swizzled + w_lin^T + irfft coefficient matrix
__global__ __launch_bounds__(256) void k0b_prep(const float* __restrict__ wb1,
                                                const float* __restrict__ wf1,
                                                const float* __restrict__ wb2,
                                                const float* __restrict__ wf2,
                                                const float* __restrict__ wl,
                                                unsigned short* __restrict__ w1bt,
                                                unsigned short* __restrict__ w2bt,
                                                unsigned short* __restrict__ wlt_pre,
                                                unsigned short* __restrict__ ctb_pre)
{
    int tgt = blockIdx.x * 256 + threadIdx.x;   // 0..40959
    if (tgt < 16384) {
        int head = tgt >> 13;
        int o = (tgt >> 6) & 127;
        int i = tgt & 63;
        const float* src = head ? wf1 : wb1;    // [64][128]
        int dst = head * 8192 + o * 64 + (((i >> 3) ^ (o & 7)) << 3) + (i & 7);
        w1bt[dst] = f2bf(src[i * 128 + o]);
    } else if (tgt < 32768) {
        int u = tgt - 16384;
        int head = u >> 13;
        int o = (u >> 7) & 63;
        int c = u & 127;
        const float* src = head ? wf2 : wb2;    // [128][64]
        int dst = head * 8192 + o * 128 + (((c >> 3) ^ (o & 7)) << 3) + (c & 7);
        w2bt[dst] = f2bf(src[c * 64 + o]);
    } else if (tgt < 36864) {
        int u = tgt - 32768;                    // 0..4095
        int o = u >> 6, i = u & 63;
        int chunk = (i >> 3) ^ (o & 7);
        wlt_pre[o * 64 + chunk * 8 + (i & 7)] = f2bf(wl[i * 64 + o]);
    } else {
        int u = tgt - 36864;                    // 0..4095
        int v = u >> 5, k = u & 31;             // v 0..127, k 0..31
        float val;
        if (k < 16) {
            val = (k == 0) ? (1.0f / 128.0f)
                           : (2.0f / 128.0f) * cosf(TWO_PI * k * v * (1.0f / 128.0f));
        } else {
            int q = k - 16;
            val = (q == 0) ? 0.f
                           : -(2.0f / 128.0f) * sinf(TWO_PI * q * v * (1.0f / 128.0f));
        }
        int chunk = (k >> 3) ^ ((v >> 1) & 3);
        ctb_pre[v * 32 + chunk * 8 + (k & 7)] = f2bf(val);
    }
}

// k1: A[b,m,kv,i] = sum_n x[b,m,n,i] e^{-2pi i kv n/128}; packed bf16 write.
// Table version (measured better than rotator in R7 A/B).
__global__ __launch_bounds__(256) void k1_dft_n(const float* __restrict__ x,
                                                unsigned int* __restrict__ A)
{
    __shared__ float Xs[128][64];
    __shared__ __align__(8) float2 tcs[128];
    const int t = threadIdx.x;
    const int bm = blockIdx.x;
    if (t < 128) { float a = t * (TWO_PI / 128.0f); tcs[t] = make_float2(cosf(a), sinf(a)); }
    const float4* xg4 = (const float4*)(x + (size_t)bm * 8192);
    float4* Xs4 = (float4*)&Xs[0][0];
    for (int k = t; k < 2048; k += 256) Xs4[k] = xg4[k];
    __syncthreads();
    const int i = t & 63;
    const int kv0 = (t >> 6) << 2;
    float re[4] = {0.f, 0.f, 0.f, 0.f}, im[4] = {0.f, 0.f, 0.f, 0.f};
    for (int n = 0; n < 128; ++n) {
        float v = Xs[n][i];
        #pragma unroll
        for (int j = 0; j < 4; ++j) {
            int idx = ((kv0 + j) * n) & 127;
            float2 w = tcs[idx];
            re[j] += v * w.x;
            im[j] -= v * w.y;
        }
    }
    unsigned int* Ap = A + (size_t)bm * 1024;
    #pragma unroll
    for (int j = 0; j < 4; ++j)
        Ap[(kv0 + j) * 64 + i] = (unsigned)f2bf(re[j]) | ((unsigned)f2bf(im[j]) << 16);
}

// k2: xft[b,p,kv,i] = (1/128) sum_m A[b,m,kv,i] e^{-2pi i km(p) m/128}.
// Table version; As packed u32 (32KB LDS -> 4 blocks/CU).
__global__ __launch_bounds__(256) void k2_dft_m(const unsigned int* __restrict__ A,
                                                float2* __restrict__ xft)
{
    __shared__ unsigned int As[128][64];
    __shared__ __align__(8) float2 tcs[128];
    const int t = threadIdx.x;
    const int b = blockIdx.x >> 4, kv = blockIdx.x & 15;
    if (t < 128) { float a = t * (TWO_PI / 128.0f); tcs[t] = make_float2(cosf(a), sinf(a)); }
    for (int k = t; k < 4096; k += 256) {
        int m = k >> 5, i2 = (k & 31) << 1;
        *(uint2*)&As[m][i2] =
            *(const uint2*)&A[((size_t)(b * 128 + m) * 16 + kv) * 64 + i2];
    }
    __syncthreads();
    const int i = t & 63;
    const int p0 = (t >> 6) << 3;
    float2 acc[8];
    #pragma unroll
    for (int j = 0; j < 8; ++j) acc[j] = make_float2(0.f, 0.f);
    for (int m = 0; m < 128; ++m) {
        unsigned pk = As[m][i];
        float ax = __uint_as_float(pk << 16);
        float ay = __uint_as_float(pk & 0xffff0000u);
        #pragma unroll
        for (int j = 0; j < 8; ++j) {
            int p = p0 + j;
            int km = (p < 16) ? p : (96 + p);     // p>=16 -> km = 112 + (p-16)
            int idx = (km * m) & 127;
            float2 cs = tcs[idx];
            acc[j].x += ax * cs.x + ay * cs.y;    // a * e^{-i th}
            acc[j].y += ay * cs.x - ax * cs.y;
        }
    }
    const float sc = 1.0f / 128.0f;
    #pragma unroll
    for (int j = 0; j < 8; ++j)
        xft[((size_t)(b * 32 + p0 + j) * 16 + kv) * 64 + i] =
            make_float2(acc[j].x * sc, acc[j].y * sc);
}

// k3a: c1[b,p,kv,j] = sum_i xft[b,p,kv,i] * w0c[i,j,p]
__global__ __launch_bounds__(256) void k3a_spec1(const float2* __restrict__ xft,
                                                 const float2* __restrict__ w0t,
                                                 float2* __restrict__ c1)
{
    __shared__ __align__(16) float2 xs[16][64];
    __shared__ __align__(16) float2 w0s[64][64];
    const int t = threadIdx.x;
    const int b = blockIdx.x >> 5, p = blockIdx.x & 31;
    const float2* xg = xft + (size_t)(b * 32 + p) * 1024;
    for (int k = t; k < 1024; k += 256) ((float2*)xs)[k] = xg[k];
    const float4* wg = (const float4*)(w0t + (size_t)p * 4096);
    for (int k = t; k < 2048; k += 256) ((float4*)w0s)[k] = wg[k];
    __syncthreads();
    const int j = t & 63;
    const int kv0 = (t >> 6) << 2;
    float2 acc[4];
    #pragma unroll
    for (int q = 0; q < 4; ++q) acc[q] = make_float2(0.f, 0.f);
    for (int i = 0; i < 64; ++i) {
        float2 w = w0s[i][j];
        #pragma unroll
        for (int q = 0; q < 4; ++q) {
            float2 a = xs[kv0 + q][i];
            acc[q].x += a.x * w.x - a.y * w.y;
            acc[q].y += a.x * w.y + a.y * w.x;
        }
    }
    #pragma unroll
    for (int q = 0; q < 4; ++q)
        c1[((size_t)(b * 32 + p) * 16 + kv0 + q) * 64 + j] = acc[q];
}

// k3b: oft[b,p,kv,o] = sum_j c1[b,p,kv,j] * w1c[j,o,kv]  (weights per half h=p/16)
__global__ __launch_bounds__(256) void k3b_spec2(const float2* __restrict__ c1,
                                                 const float2* __restrict__ w1t,
                                                 float2* __restrict__ oft)
{
    __shared__ __align__(16) float2 cs[16][64];
    __shared__ __align__(16) float2 w1s[64][64];
    const int t = threadIdx.x;
    int id = blockIdx.x;
    const int h = id & 1; id >>= 1;
    const int kv = id & 15; const int b = id >> 4;
    for (int k = t; k < 1024; k += 256) {
        int pp = k >> 6, j = k & 63;
        cs[pp][j] = c1[((size_t)(b * 32 + h * 16 + pp) * 16 + kv) * 64 + j];
    }
    const float4* wg = (const float4*)(w1t + (size_t)(h * 16 + kv) * 4096);
    for (int k = t; k < 2048; k += 256) ((float4*)w1s)[k] = wg[k];
    __syncthreads();
    const int o = t & 63;
    const int pp0 = (t >> 6) << 2;
    float2 acc[4];
    #pragma unroll
    for (int q = 0; q < 4; ++q) acc[q] = make_float2(0.f, 0.f);
    for (int j = 0; j < 64; ++j) {
        float2 w = w1s[j][o];
        #pragma unroll
        for (int q = 0; q < 4; ++q) {
            float2 a = cs[pp0 + q][j];
            acc[q].x += a.x * w.x - a.y * w.y;
            acc[q].y += a.x * w.y + a.y * w.x;
        }
    }
    #pragma unroll
    for (int q = 0; q < 4; ++q)
        oft[((size_t)(b * 32 + h * 16 + pp0 + q) * 16 + kv) * 64 + o] = acc[q];
}

// k4: T[b,u,q,o] = sum_p oft[b,p,q,o] e^{+2pi i km(p) u/128}; packed bf16 write.
__global__ __launch_bounds__(256) void k4_idft_m(const float2* __restrict__ oft,
                                                 unsigned int* __restrict__ T)
{
    __shared__ float2 Os[32][64];
    __shared__ __align__(8) float2 tcs[128];
    const int t = threadIdx.x;
    const int b = blockIdx.x >> 4, q = blockIdx.x & 15;
    if (t < 128) { float a = t * (TWO_PI / 128.0f); tcs[t] = make_float2(cosf(a), sinf(a)); }
    for (int k = t; k < 2048; k += 256) {
        int p = k >> 6, o = k & 63;
        Os[p][o] = oft[((size_t)(b * 32 + p) * 16 + q) * 64 + o];
    }
    __syncthreads();
    const int o = t & 63;
    const int u0 = (t >> 6) << 5;
    float2 op[32];
    #pragma unroll
    for (int p = 0; p < 32; ++p) op[p] = Os[p][o];
    for (int du = 0; du < 32; ++du) {
        int u = u0 + du;
        float ax = 0.f, ay = 0.f;
        #pragma unroll
        for (int p = 0; p < 32; ++p) {
            int km = (p < 16) ? p : (96 + p);
            int idx = (km * u) & 127;
            float2 cs = tcs[idx];
            ax += op[p].x * cs.x - op[p].y * cs.y;  // a * e^{+i th}
            ay += op[p].x * cs.y + op[p].y * cs.x;
        }
        T[((size_t)(b * 128 + u) * 16 + q) * 64 + o] =
            (unsigned)f2bf(ax) | ((unsigned)f2bf(ay) << 16);
    }
}

// k56 v5: R6 structure + early x-load hoist + packed-T + pre-swizzled weights.
// One block per bm=(b,u), 4 waves, wave owns 32 rows. LDS 68K -> 2 blocks/CU.
// 5 barriers. RA (20K: Ctb|wlt|Tpk, dead after phase A) reused for w2s.
__global__ __launch_bounds__(256) void k56_fused(
    const float* __restrict__ x, const unsigned int* __restrict__ Tg,
    const float* __restrict__ bl,
    const unsigned short* __restrict__ ctb_pre, const unsigned short* __restrict__ wlt_pre,
    const unsigned short* __restrict__ w1bt, const unsigned short* __restrict__ w2bt,
    const float* __restrict__ bb1, const float* __restrict__ bb2,
    const float* __restrict__ bf1, const float* __restrict__ bf2,
    float* __restrict__ out)
{
    __shared__ __align__(16) unsigned char RA[20480];    // Ctb 8K | wlt 8K | Tpk 4K -> w2s 16K
    __shared__ __align__(16) unsigned short w1s[8192];   // [o:128][k:64] swizzled
    __shared__ __align__(16) unsigned short ys[8192];    // [v:128][o:64] swizzled
    __shared__ __align__(16) unsigned short hs[8192];    // 4 waves x [16][128] swizzled

    unsigned short* Ctb = (unsigned short*)RA;           // [v:128][k:32]
    unsigned short* wlt = (unsigned short*)(RA + 8192);  // [o:64][k:64]
    unsigned short* Tpk = (unsigned short*)(RA + 16384); // [o:64][k:32]
    unsigned short* w2s = (unsigned short*)RA;           // [o:64][k:128]

    const int t = threadIdx.x;
    const int bm = blockIdx.x;
    const int lane = t & 63, wv = t >> 6;
    const int ar = lane & 15, kg = lane >> 4;
    const int R0 = wv * 32;

    // ---- 0) EARLY: x loads into registers (drain under staging + B1) ----
    float4 xr[2][4];
    #pragma unroll
    for (int rt = 0; rt < 2; ++rt) {
        const float* xp = x + (size_t)bm * 8192 + (R0 + rt * 16 + ar) * 64 + kg * 8;
        xr[rt][0] = *(const float4*)(xp);
        xr[rt][1] = *(const float4*)(xp + 4);
        xr[rt][2] = *(const float4*)(xp + 32);
        xr[rt][3] = *(const float4*)(xp + 36);
    }

    // ---- 1) stage: Ctb/wlt/w1s(head0) straight copies; Tpk unpack ----
    {
        const uint4* cg = (const uint4*)ctb_pre;
        for (int k = t; k < 512; k += 256) ((uint4*)Ctb)[k] = cg[k];
        const uint4* wg = (const uint4*)wlt_pre;
        for (int k = t; k < 512; k += 256) ((uint4*)wlt)[k] = wg[k];
        const uint4* g1 = (const uint4*)w1bt;
        for (int k = t; k < 1024; k += 256) ((uint4*)w1s)[k] = g1[k];
        const unsigned int* Tp = Tg + (size_t)bm * 1024;
        for (int idx = t; idx < 1024; idx += 256) {
            int q = idx >> 6, o = idx & 63;
            unsigned v = Tp[idx];
            int f = (o >> 1) & 3;
            Tpk[o * 32 + (((q >> 3) ^ f) << 3) + (q & 7)] = (unsigned short)(v & 0xffffu);
            Tpk[o * 32 + (((2 + (q >> 3)) ^ f) << 3) + (q & 7)] = (unsigned short)(v >> 16);
        }
    }
    __syncthreads();   // B1

    float biasl[4];
    #pragma unroll
    for (int ct = 0; ct < 4; ++ct) biasl[ct] = bl[ct * 16 + ar];

    // ---- phase A: y rows via MFMA (residual + spectral assembly) ----
    #pragma unroll
    for (int rt = 0; rt < 2; ++rt) {
        const int vrow = R0 + rt * 16 + ar;
        bf16x8 a0 = cvt8(xr[rt][0], xr[rt][1]);
        bf16x8 a1 = cvt8(xr[rt][2], xr[rt][3]);
        bf16x8 asp = *(const bf16x8*)&Ctb[vrow * 32 + ((kg ^ ((vrow >> 1) & 3)) << 3)];
        f32x4 acc[4];
        #pragma unroll
        for (int ct = 0; ct < 4; ++ct) acc[ct] = (f32x4){0.f, 0.f, 0.f, 0.f};
        #pragma unroll
        for (int ct = 0; ct < 4; ++ct) {
            int o = ct * 16 + ar;
            bf16x8 b0 = *(const bf16x8*)&wlt[o * 64 + ((kg ^ (o & 7)) << 3)];
            bf16x8 b1 = *(const bf16x8*)&wlt[o * 64 + (((4 + kg) ^ (o & 7)) << 3)];
            bf16x8 bsp = *(const bf16x8*)&Tpk[o * 32 + ((kg ^ ((o >> 1) & 3)) << 3)];
            acc[ct] = __builtin_amdgcn_mfma_f32_16x16x32_bf16(a0, b0, acc[ct], 0, 0, 0);
            acc[ct] = __builtin_amdgcn_mfma_f32_16x16x32_bf16(a1, b1, acc[ct], 0, 0, 0);
            acc[ct] = __builtin_amdgcn_mfma_f32_16x16x32_bf16(asp, bsp, acc[ct], 0, 0, 0);
        }
        #pragma unroll
        for (int ct = 0; ct < 4; ++ct) {
            int col = ct * 16 + ar;
            #pragma unroll
            for (int r = 0; r < 4; ++r) {
                int row = R0 + rt * 16 + kg * 4 + r;
                float v = fmaxf(acc[ct][r] + biasl[ct], 0.f);
                ys[row * 64 + (((col >> 3) ^ (row & 7)) << 3) + (col & 7)] = f2bf(v);
            }
        }
    }
    __syncthreads();   // B2: RA dead -> w2s region

    // ---- phase B: heads; weights in LDS (straight copies, pre-swizzled) ----
    unsigned short* hw = hs + wv * 2048;   // [16][128] wave-private
    for (int head = 0; head < 2; ++head) {
        if (head) {
            const uint4* g1 = (const uint4*)(w1bt + 8192);
            for (int k = t; k < 1024; k += 256) ((uint4*)w1s)[k] = g1[k];
        }
        {
            const uint4* g2 = (const uint4*)(w2bt + head * 8192);
            for (int k = t; k < 1024; k += 256) ((uint4*)w2s)[k] = g2[k];
        }
        const float* B1 = head ? bf1 : bb1;
        const float* B2 = head ? bf2 : bb2;
        float bias1[8], bias2[4];
        #pragma unroll
        for (int c = 0; c < 8; ++c) bias1[c] = B1[c * 16 + ar];
        #pragma unroll
        for (int c = 0; c < 4; ++c) bias2[c] = B2[c * 16 + ar];
        __syncthreads();   // B3 / B5

        #pragma unroll
        for (int rt = 0; rt < 2; ++rt) {
            const int rowbase = R0 + rt * 16;
            // GEMM1: 16x128, K=64. A from ys, B from w1s.
            const int yrow = rowbase + ar;
            bf16x8 ya0 = *(const bf16x8*)&ys[yrow * 64 + ((kg ^ (yrow & 7)) << 3)];
            bf16x8 ya1 = *(const bf16x8*)&ys[yrow * 64 + (((4 + kg) ^ (yrow & 7)) << 3)];
            f32x4 acc1[8];
            #pragma unroll
            for (int ct = 0; ct < 8; ++ct) acc1[ct] = (f32x4){0.f, 0.f, 0.f, 0.f};
            #pragma unroll
            for (int ct = 0; ct < 8; ++ct) {
                int brow = ct * 16 + ar;
                bf16x8 b0 = *(const bf16x8*)&w1s[brow * 64 + ((kg ^ (brow & 7)) << 3)];
                bf16x8 b1 = *(const bf16x8*)&w1s[brow * 64 + (((4 + kg) ^ (brow & 7)) << 3)];
                acc1[ct] = __builtin_amdgcn_mfma_f32_16x16x32_bf16(ya0, b0, acc1[ct], 0, 0, 0);
                acc1[ct] = __builtin_amdgcn_mfma_f32_16x16x32_bf16(ya1, b1, acc1[ct], 0, 0, 0);
            }
            #pragma unroll
            for (int ct = 0; ct < 8; ++ct) {
                #pragma unroll
                for (int r = 0; r < 4; ++r) {
                    int row = kg * 4 + r;          // wave-local 0..15
                    int col = ct * 16 + ar;
                    float v = fmaxf(acc1[ct][r] + bias1[ct], 0.f);
                    hw[row * 128 + (((col >> 3) ^ (row & 7)) << 3) + (col & 7)] = f2bf(v);
                }
            }
            // GEMM2: 16x64, K=128. A from hw, B from w2s.
            f32x4 acc2[4];
            #pragma unroll
            for (int ct = 0; ct < 4; ++ct) acc2[ct] = (f32x4){0.f, 0.f, 0.f, 0.f};
            #pragma unroll
            for (int ks = 0; ks < 4; ++ks) {
                bf16x8 a = *(const bf16x8*)&hw[ar * 128 + (((ks * 4 + kg) ^ (ar & 7)) << 3)];
                #pragma unroll
                for (int ct = 0; ct < 4; ++ct) {
                    int brow = ct * 16 + ar;
                    bf16x8 b = *(const bf16x8*)&w2s[brow * 128 + (((ks * 4 + kg) ^ (ar & 7)) << 3)];
                    acc2[ct] = __builtin_amdgcn_mfma_f32_16x16x32_bf16(a, b, acc2[ct], 0, 0, 0);
                }
            }
            float* og = out + (size_t)head * 33554432u + (size_t)bm * 8192;
            #pragma unroll
            for (int ct = 0; ct < 4; ++ct) {
                #pragma unroll
                for (int r = 0; r < 4; ++r)
                    og[(size_t)(rowbase + kg * 4 + r) * 64 + ct * 16 + ar] =
                        acc2[ct][r] + bias2[ct];
            }
        }
        if (head == 0) __syncthreads();   // B4
    }
}

extern "C" void kernel_launch(void* const* d_in, const int* in_sizes, int n_in,
                              void* d_out, int out_size, void* d_ws, size_t ws_size,
                              hipStream_t stream)
{
    (void)in_sizes; (void)n_in; (void)out_size; (void)ws_size;
    const float* x   = (const float*)d_in[0];
    const float* ws0 = (const float*)d_in[1];
    const float* ws1 = (const float*)d_in[2];
    const float* wl  = (const float*)d_in[3];
    const float* bl  = (const float*)d_in[4];
    const float* wb1 = (const float*)d_in[5];
    const float* bb1 = (const float*)d_in[6];
    const float* wb2 = (const float*)d_in[7];
    const float* bb2 = (const float*)d_in[8];
    const float* wf1 = (const float*)d_in[9];
    const float* bf1 = (const float*)d_in[10];
    const float* wf2 = (const float*)d_in[11];
    const float* bf2 = (const float*)d_in[12];
    float* out = (float*)d_out;

    float* ws = (float*)d_ws;
    float2* w0t = (float2*)ws;                       // 131072 float2
    float2* w1t = (float2*)(ws + 262144);            // 131072 float2
    unsigned int* Tb  = (unsigned int*)(ws + 524288);    // 4194304 u32 packed
    unsigned int* Ab  = (unsigned int*)(ws + 8912896);   // 4194304 u32 packed
    float2* xft = (float2*)(ws + 17301504);          // 1048576 float2
    float2* c1b = (float2*)(ws + 19398656);          // 1048576 float2
    float2* oft = (float2*)(ws + 21495808);          // 1048576 float2
    unsigned short* w1bt    = (unsigned short*)(ws + 23592960);  // 16384 u16
    unsigned short* w2bt    = (unsigned short*)(ws + 23601152);  // 16384 u16
    unsigned short* wlt_pre = (unsigned short*)(ws + 23609344);  // 4096 u16
    unsigned short* ctb_pre = (unsigned short*)(ws + 23611392);  // 4096 u16

    k0_prep    <<<1024, 256, 0, stream>>>(ws0, ws1, w0t, w1t);
    k0b_prep   <<<160,  256, 0, stream>>>(wb1, wf1, wb2, wf2, wl,
                                          w1bt, w2bt, wlt_pre, ctb_pre);
    k1_dft_n   <<<4096, 256, 0, stream>>>(x, Ab);
    k2_dft_m   <<<512,  256, 0, stream>>>(Ab, xft);
    k3a_spec1  <<<1024, 256, 0, stream>>>(xft, w0t, c1b);
    k3b_spec2  <<<1024, 256, 0, stream>>>(c1b, w1t, oft);
    k4_idft_m  <<<512,  256, 0, stream>>>(oft, Tb);
    k56_fused  <<<4096, 256, 0, stream>>>(x, Tb, bl, ctb_pre, wlt_pre,
                                          w1bt, w2bt, bb1, bb2, bf1, bf2, out);
}

// Round 9
// 298.400 us; speedup vs baseline: 1.3979x; 1.1617x over previous
//
#include <hip/hip_runtime.h>
#include <hip/hip_bf16.h>

#define TWO_PI 6.28318530717958647692f

typedef __attribute__((ext_vector_type(8))) short bf16x8;
typedef __attribute__((ext_vector_type(4))) float f32x4;

__device__ __forceinline__ unsigned short f2bf(float v) {
    __hip_bfloat16 h = __float2bfloat16(v);
    return *(unsigned short*)&h;
}

__device__ __forceinline__ bf16x8 cvt8(float4 a, float4 b) {
    bf16x8 r;
    r[0] = (short)f2bf(a.x); r[1] = (short)f2bf(a.y);
    r[2] = (short)f2bf(a.z); r[3] = (short)f2bf(a.w);
    r[4] = (short)f2bf(b.x); r[5] = (short)f2bf(b.y);
    r[6] = (short)f2bf(b.z); r[7] = (short)f2bf(b.w);
    return r;
}

// Problem: B=32, M=N=128, I=O=64, NM=16.
// Spectral path keeps km in {0..15,112..127} (p=0..31), kn=0..15 (q).
// Spectral branch contributes ~1e-6 abs to y -> bf16 anywhere in it is free.
// A and T are packed bf16 pairs (u32: re low, im high).
//
// R5 lesson: MFMA operands must come from LDS/regs.
// R7 lesson: W2-in-regs + per-head restage regressed.
// R9: k1 is a GEMM (16x64 out, K=128 per (b,m)) -> MFMA with padded-stride
//     transposed x staging (no swizzle risk).
//
// ws layout (float offsets):
//   w0t     @ 0        : 262144   (32 p x 64 i x 64 j complex fp32)
//   w1t     @ 262144   : 262144   (2 h x 16 kv x 64 j x 64 o complex fp32)
//   T       @ 524288   : 4194304 u32 packed bf16 (b,u,q,o)
//   A       @ 8912896  : 4194304 u32 packed bf16 (b,m,kv,i)
//   xft     @ 17301504 : 2097152 fp32
//   c1      @ 19398656 : 2097152 fp32
//   oft     @ 21495808 : 2097152 fp32
//   w1bt    @ 23592960 : 16384 u16  W1t[2][o:128][k:64] bf16 PRE-SWIZZLED
//   w2bt    @ 23601152 : 16384 u16  W2t[2][o:64][k:128] bf16 PRE-SWIZZLED
//   wlt_pre @ 23609344 : 4096 u16   w_lin^T bf16 pre-swizzled
//   ctb_pre @ 23611392 : 4096 u16   irfft coeff bf16 pre-swizzled
//   wdft    @ 23613440 : 4352 u16   DFT matrix [c:2][kv:16][n:136 pad] bf16

__global__ __launch_bounds__(256) void k0_prep(const float* __restrict__ ws0,
                                               const float* __restrict__ ws1,
                                               float2* __restrict__ w0t,
                                               float2* __restrict__ w1t)
{
    int tgt = blockIdx.x * 256 + threadIdx.x;   // 0..262143
    if (tgt < 131072) {
        int p = tgt >> 12;
        int rem = tgt & 4095;
        int i = rem >> 6, j = rem & 63;
        const float* s = (p < 16) ? ws0 : ws1;   // f=0 plane
        int px = p & 15;
        int base = ((i * 64 + j) * 16 + px) * 2;
        w0t[tgt] = make_float2(s[base], s[base + 1]);
    } else {
        int u = tgt - 131072;
        int h = u >> 16;
        int kv = (u >> 12) & 15;
        int j = (u >> 6) & 63;
        int o = u & 63;
        const float* s = (h ? ws1 : ws0) + 131072;  // f=1 plane
        int base = ((j * 64 + o) * 16 + kv) * 2;
        w1t[u] = make_float2(s[base], s[base + 1]);
    }
}

// head weights bf16 pre-swizzled + w_lin^T + irfft coeffs + DFT matrix
__global__ __launch_bounds__(256) void k0b_prep(const float* __restrict__ wb1,
                                                const float* __restrict__ wf1,
                                                const float* __restrict__ wb2,
                                                const float* __restrict__ wf2,
                                                const float* __restrict__ wl,
                                                unsigned short* __restrict__ w1bt,
                                                unsigned short* __restrict__ w2bt,
                                                unsigned short* __restrict__ wlt_pre,
                                                unsigned short* __restrict__ ctb_pre,
                                                unsigned short* __restrict__ wdft)
{
    int tgt = blockIdx.x * 256 + threadIdx.x;   // 0..45311
    if (tgt < 16384) {
        int head = tgt >> 13;
        int o = (tgt >> 6) & 127;
        int i = tgt & 63;
        const float* src = head ? wf1 : wb1;    // [64][128]
        int dst = head * 8192 + o * 64 + (((i >> 3) ^ (o & 7)) << 3) + (i & 7);
        w1bt[dst] = f2bf(src[i * 128 + o]);
    } else if (tgt < 32768) {
        int u = tgt - 16384;
        int head = u >> 13;
        int o = (u >> 7) & 63;
        int c = u & 127;
        const float* src = head ? wf2 : wb2;    // [128][64]
        int dst = head * 8192 + o * 128 + (((c >> 3) ^ (o & 7)) << 3) + (c & 7);
        w2bt[dst] = f2bf(src[c * 64 + o]);
    } else if (tgt < 36864) {
        int u = tgt - 32768;                    // 0..4095
        int o = u >> 6, i = u & 63;
        int chunk = (i >> 3) ^ (o & 7);
        wlt_pre[o * 64 + chunk * 8 + (i & 7)] = f2bf(wl[i * 64 + o]);
    } else if (tgt < 40960) {
        int u = tgt - 36864;                    // 0..4095
        int v = u >> 5, k = u & 31;             // v 0..127, k 0..31
        float val;
        if (k < 16) {
            val = (k == 0) ? (1.0f / 128.0f)
                           : (2.0f / 128.0f) * cosf(TWO_PI * k * v * (1.0f / 128.0f));
        } else {
            int q = k - 16;
            val = (q == 0) ? 0.f
                           : -(2.0f / 128.0f) * sinf(TWO_PI * q * v * (1.0f / 128.0f));
        }
        int chunk = (k >> 3) ^ ((v >> 1) & 3);
        ctb_pre[v * 32 + chunk * 8 + (k & 7)] = f2bf(val);
    } else {
        int u = tgt - 40960;                    // 0..4351
        int c = u / 2176;
        int rem = u - c * 2176;
        int kv = rem / 136, n = rem - (rem / 136) * 136;
        float val = 0.f;
        if (n < 128) {
            int idx = (kv * n) & 127;
            float th = (float)idx * (TWO_PI / 128.0f);
            val = c ? -sinf(th) : cosf(th);
        }
        wdft[u] = f2bf(val);
    }
}

// k1 v3 (MFMA): A[b,m,kv,i] = sum_n W[kv,n] x[b,m,n,i], packed bf16 u32 out.
// Per block = one (b,m): stage x transposed Xt[i][n] bf16 (pad stride 136),
// DFT matrix Wl[2][16][136]; wave w computes the 16kv x 16i tile i in
// [16w,16w+16). 8 MFMA per wave. LDS 26KB -> 6 blocks/CU.
__global__ __launch_bounds__(256) void k1_dft_n(const float* __restrict__ x,
                                                const unsigned short* __restrict__ wdft,
                                                unsigned int* __restrict__ A)
{
    __shared__ __align__(16) unsigned short Xt[64 * 136];    // 17408 B
    __shared__ __align__(16) unsigned short Wl[2 * 16 * 136];//  8704 B
    const int t = threadIdx.x;
    const int bm = blockIdx.x;
    {   // stage DFT matrix (straight copy; global layout == LDS layout)
        const uint4* wg = (const uint4*)wdft;
        uint4* wl = (uint4*)Wl;
        for (int k = t; k < 544; k += 256) wl[k] = wg[k];
    }
    {   // stage x transposed: lane=i coalesced reads, b64 packed writes
        const float* xg = x + (size_t)bm * 8192;
        const int i = t & 63, q = t >> 6;
        #pragma unroll
        for (int pass = 0; pass < 8; ++pass) {
            int n0 = pass * 16 + q * 4;
            float v0 = xg[(n0 + 0) * 64 + i];
            float v1 = xg[(n0 + 1) * 64 + i];
            float v2 = xg[(n0 + 2) * 64 + i];
            float v3 = xg[(n0 + 3) * 64 + i];
            unsigned lo = (unsigned)f2bf(v0) | ((unsigned)f2bf(v1) << 16);
            unsigned hi = (unsigned)f2bf(v2) | ((unsigned)f2bf(v3) << 16);
            *(uint2*)&Xt[i * 136 + n0] = make_uint2(lo, hi);
        }
    }
    __syncthreads();
    const int lane = t & 63, wv = t >> 6;
    const int ar = lane & 15, kg = lane >> 4;
    f32x4 are = (f32x4){0.f, 0.f, 0.f, 0.f};
    f32x4 aim = (f32x4){0.f, 0.f, 0.f, 0.f};
    #pragma unroll
    for (int ks = 0; ks < 4; ++ks) {
        int off = ks * 32 + kg * 8;
        bf16x8 b   = *(const bf16x8*)&Xt[(wv * 16 + ar) * 136 + off];  // B[k][i]
        bf16x8 wre = *(const bf16x8*)&Wl[ar * 136 + off];              // A rows=kv
        bf16x8 wim = *(const bf16x8*)&Wl[(16 + ar) * 136 + off];
        are = __builtin_amdgcn_mfma_f32_16x16x32_bf16(wre, b, are, 0, 0, 0);
        aim = __builtin_amdgcn_mfma_f32_16x16x32_bf16(wim, b, aim, 0, 0, 0);
    }
    unsigned int* Ap = A + (size_t)bm * 1024;
    #pragma unroll
    for (int r = 0; r < 4; ++r) {
        int kv = kg * 4 + r;
        int i = wv * 16 + ar;
        Ap[kv * 64 + i] = (unsigned)f2bf(are[r]) | ((unsigned)f2bf(aim[r]) << 16);
    }
}

// k2: xft[b,p,kv,i] = (1/128) sum_m A[b,m,kv,i] e^{-2pi i km(p) m/128}.
__global__ __launch_bounds__(256) void k2_dft_m(const unsigned int* __restrict__ A,
                                                float2* __restrict__ xft)
{
    __shared__ unsigned int As[128][64];
    __shared__ __align__(8) float2 tcs[128];
    const int t = threadIdx.x;
    const int b = blockIdx.x >> 4, kv = blockIdx.x & 15;
    if (t < 128) { float a = t * (TWO_PI / 128.0f); tcs[t] = make_float2(cosf(a), sinf(a)); }
    for (int k = t; k < 4096; k += 256) {
        int m = k >> 5, i2 = (k & 31) << 1;
        *(uint2*)&As[m][i2] =
            *(const uint2*)&A[((size_t)(b * 128 + m) * 16 + kv) * 64 + i2];
    }
    __syncthreads();
    const int i = t & 63;
    const int p0 = (t >> 6) << 3;
    float2 acc[8];
    #pragma unroll
    for (int j = 0; j < 8; ++j) acc[j] = make_float2(0.f, 0.f);
    for (int m = 0; m < 128; ++m) {
        unsigned pk = As[m][i];
        float ax = __uint_as_float(pk << 16);
        float ay = __uint_as_float(pk & 0xffff0000u);
        #pragma unroll
        for (int j = 0; j < 8; ++j) {
            int p = p0 + j;
            int km = (p < 16) ? p : (96 + p);     // p>=16 -> km = 112 + (p-16)
            int idx = (km * m) & 127;
            float2 cs = tcs[idx];
            acc[j].x += ax * cs.x + ay * cs.y;    // a * e^{-i th}
            acc[j].y += ay * cs.x - ax * cs.y;
        }
    }
    const float sc = 1.0f / 128.0f;
    #pragma unroll
    for (int j = 0; j < 8; ++j)
        xft[((size_t)(b * 32 + p0 + j) * 16 + kv) * 64 + i] =
            make_float2(acc[j].x * sc, acc[j].y * sc);
}

// k3a: c1[b,p,kv,j] = sum_i xft[b,p,kv,i] * w0c[i,j,p]
__global__ __launch_bounds__(256) void k3a_spec1(const float2* __restrict__ xft,
                                                 const float2* __restrict__ w0t,
                                                 float2* __restrict__ c1)
{
    __shared__ __align__(16) float2 xs[16][64];
    __shared__ __align__(16) float2 w0s[64][64];
    const int t = threadIdx.x;
    const int b = blockIdx.x >> 5, p = blockIdx.x & 31;
    const float2* xg = xft + (size_t)(b * 32 + p) * 1024;
    for (int k = t; k < 1024; k += 256) ((float2*)xs)[k] = xg[k];
    const float4* wg = (const float4*)(w0t + (size_t)p * 4096);
    for (int k = t; k < 2048; k += 256) ((float4*)w0s)[k] = wg[k];
    __syncthreads();
    const int j = t & 63;
    const int kv0 = (t >> 6) << 2;
    float2 acc[4];
    #pragma unroll
    for (int q = 0; q < 4; ++q) acc[q] = make_float2(0.f, 0.f);
    for (int i = 0; i < 64; ++i) {
        float2 w = w0s[i][j];
        #pragma unroll
        for (int q = 0; q < 4; ++q) {
            float2 a = xs[kv0 + q][i];
            acc[q].x += a.x * w.x - a.y * w.y;
            acc[q].y += a.x * w.y + a.y * w.x;
        }
    }
    #pragma unroll
    for (int q = 0; q < 4; ++q)
        c1[((size_t)(b * 32 + p) * 16 + kv0 + q) * 64 + j] = acc[q];
}

// k3b: oft[b,p,kv,o] = sum_j c1[b,p,kv,j] * w1c[j,o,kv]
__global__ __launch_bounds__(256) void k3b_spec2(const float2* __restrict__ c1,
                                                 const float2* __restrict__ w1t,
                                                 float2* __restrict__ oft)
{
    __shared__ __align__(16) float2 cs[16][64];
    __shared__ __align__(16) float2 w1s[64][64];
    const int t = threadIdx.x;
    int id = blockIdx.x;
    const int h = id & 1; id >>= 1;
    const int kv = id & 15; const int b = id >> 4;
    for (int k = t; k < 1024; k += 256) {
        int pp = k >> 6, j = k & 63;
        cs[pp][j] = c1[((size_t)(b * 32 + h * 16 + pp) * 16 + kv) * 64 + j];
    }
    const float4* wg = (const float4*)(w1t + (size_t)(h * 16 + kv) * 4096);
    for (int k = t; k < 2048; k += 256) ((float4*)w1s)[k] = wg[k];
    __syncthreads();
    const int o = t & 63;
    const int pp0 = (t >> 6) << 2;
    float2 acc[4];
    #pragma unroll
    for (int q = 0; q < 4; ++q) acc[q] = make_float2(0.f, 0.f);
    for (int j = 0; j < 64; ++j) {
        float2 w = w1s[j][o];
        #pragma unroll
        for (int q = 0; q < 4; ++q) {
            float2 a = cs[pp0 + q][j];
            acc[q].x += a.x * w.x - a.y * w.y;
            acc[q].y += a.x * w.y + a.y * w.x;
        }
    }
    #pragma unroll
    for (int q = 0; q < 4; ++q)
        oft[((size_t)(b * 32 + h * 16 + pp0 + q) * 16 + kv) * 64 + o] = acc[q];
}

// k4: T[b,u,q,o] = sum_p oft[b,p,q,o] e^{+2pi i km(p) u/128}; packed bf16 write.
__global__ __launch_bounds__(256) void k4_idft_m(const float2* __restrict__ oft,
                                                 unsigned int* __restrict__ T)
{
    __shared__ float2 Os[32][64];
    __shared__ __align__(8) float2 tcs[128];
    const int t = threadIdx.x;
    const int b = blockIdx.x >> 4, q = blockIdx.x & 15;
    if (t < 128) { float a = t * (TWO_PI / 128.0f); tcs[t] = make_float2(cosf(a), sinf(a)); }
    for (int k = t; k < 2048; k += 256) {
        int p = k >> 6, o = k & 63;
        Os[p][o] = oft[((size_t)(b * 32 + p) * 16 + q) * 64 + o];
    }
    __syncthreads();
    const int o = t & 63;
    const int u0 = (t >> 6) << 5;
    float2 op[32];
    #pragma unroll
    for (int p = 0; p < 32; ++p) op[p] = Os[p][o];
    for (int du = 0; du < 32; ++du) {
        int u = u0 + du;
        float ax = 0.f, ay = 0.f;
        #pragma unroll
        for (int p = 0; p < 32; ++p) {
            int km = (p < 16) ? p : (96 + p);
            int idx = (km * u) & 127;
            float2 cs = tcs[idx];
            ax += op[p].x * cs.x - op[p].y * cs.y;  // a * e^{+i th}
            ay += op[p].x * cs.y + op[p].y * cs.x;
        }
        T[((size_t)(b * 128 + u) * 16 + q) * 64 + o] =
            (unsigned)f2bf(ax) | ((unsigned)f2bf(ay) << 16);
    }
}

// k56 v5 (unchanged from R8): all-MFMA fused tail.
__global__ __launch_bounds__(256) void k56_fused(
    const float* __restrict__ x, const unsigned int* __restrict__ Tg,
    const float* __restrict__ bl,
    const unsigned short* __restrict__ ctb_pre, const unsigned short* __restrict__ wlt_pre,
    const unsigned short* __restrict__ w1bt, const unsigned short* __restrict__ w2bt,
    const float* __restrict__ bb1, const float* __restrict__ bb2,
    const float* __restrict__ bf1, const float* __restrict__ bf2,
    float* __restrict__ out)
{
    __shared__ __align__(16) unsigned char RA[20480];    // Ctb 8K | wlt 8K | Tpk 4K -> w2s 16K
    __shared__ __align__(16) unsigned short w1s[8192];
    __shared__ __align__(16) unsigned short ys[8192];
    __shared__ __align__(16) unsigned short hs[8192];

    unsigned short* Ctb = (unsigned short*)RA;
    unsigned short* wlt = (unsigned short*)(RA + 8192);
    unsigned short* Tpk = (unsigned short*)(RA + 16384);
    unsigned short* w2s = (unsigned short*)RA;

    const int t = threadIdx.x;
    const int bm = blockIdx.x;
    const int lane = t & 63, wv = t >> 6;
    const int ar = lane & 15, kg = lane >> 4;
    const int R0 = wv * 32;

    // EARLY x loads (drain under staging + B1)
    float4 xr[2][4];
    #pragma unroll
    for (int rt = 0; rt < 2; ++rt) {
        const float* xp = x + (size_t)bm * 8192 + (R0 + rt * 16 + ar) * 64 + kg * 8;
        xr[rt][0] = *(const float4*)(xp);
        xr[rt][1] = *(const float4*)(xp + 4);
        xr[rt][2] = *(const float4*)(xp + 32);
        xr[rt][3] = *(const float4*)(xp + 36);
    }

    {
        const uint4* cg = (const uint4*)ctb_pre;
        for (int k = t; k < 512; k += 256) ((uint4*)Ctb)[k] = cg[k];
        const uint4* wg = (const uint4*)wlt_pre;
        for (int k = t; k < 512; k += 256) ((uint4*)wlt)[k] = wg[k];
        const uint4* g1 = (const uint4*)w1bt;
        for (int k = t; k < 1024; k += 256) ((uint4*)w1s)[k] = g1[k];
        const unsigned int* Tp = Tg + (size_t)bm * 1024;
        for (int idx = t; idx < 1024; idx += 256) {
            int q = idx >> 6, o = idx & 63;
            unsigned v = Tp[idx];
            int f = (o >> 1) & 3;
            Tpk[o * 32 + (((q >> 3) ^ f) << 3) + (q & 7)] = (unsigned short)(v & 0xffffu);
            Tpk[o * 32 + (((2 + (q >> 3)) ^ f) << 3) + (q & 7)] = (unsigned short)(v >> 16);
        }
    }
    __syncthreads();   // B1

    float biasl[4];
    #pragma unroll
    for (int ct = 0; ct < 4; ++ct) biasl[ct] = bl[ct * 16 + ar];

    #pragma unroll
    for (int rt = 0; rt < 2; ++rt) {
        const int vrow = R0 + rt * 16 + ar;
        bf16x8 a0 = cvt8(xr[rt][0], xr[rt][1]);
        bf16x8 a1 = cvt8(xr[rt][2], xr[rt][3]);
        bf16x8 asp = *(const bf16x8*)&Ctb[vrow * 32 + ((kg ^ ((vrow >> 1) & 3)) << 3)];
        f32x4 acc[4];
        #pragma unroll
        for (int ct = 0; ct < 4; ++ct) acc[ct] = (f32x4){0.f, 0.f, 0.f, 0.f};
        #pragma unroll
        for (int ct = 0; ct < 4; ++ct) {
            int o = ct * 16 + ar;
            bf16x8 b0 = *(const bf16x8*)&wlt[o * 64 + ((kg ^ (o & 7)) << 3)];
            bf16x8 b1 = *(const bf16x8*)&wlt[o * 64 + (((4 + kg) ^ (o & 7)) << 3)];
            bf16x8 bsp = *(const bf16x8*)&Tpk[o * 32 + ((kg ^ ((o >> 1) & 3)) << 3)];
            acc[ct] = __builtin_amdgcn_mfma_f32_16x16x32_bf16(a0, b0, acc[ct], 0, 0, 0);
            acc[ct] = __builtin_amdgcn_mfma_f32_16x16x32_bf16(a1, b1, acc[ct], 0, 0, 0);
            acc[ct] = __builtin_amdgcn_mfma_f32_16x16x32_bf16(asp, bsp, acc[ct], 0, 0, 0);
        }
        #pragma unroll
        for (int ct = 0; ct < 4; ++ct) {
            int col = ct * 16 + ar;
            #pragma unroll
            for (int r = 0; r < 4; ++r) {
                int row = R0 + rt * 16 + kg * 4 + r;
                float v = fmaxf(acc[ct][r] + biasl[ct], 0.f);
                ys[row * 64 + (((col >> 3) ^ (row & 7)) << 3) + (col & 7)] = f2bf(v);
            }
        }
    }
    __syncthreads();   // B2

    unsigned short* hw = hs + wv * 2048;
    for (int head = 0; head < 2; ++head) {
        if (head) {
            const uint4* g1 = (const uint4*)(w1bt + 8192);
            for (int k = t; k < 1024; k += 256) ((uint4*)w1s)[k] = g1[k];
        }
        {
            const uint4* g2 = (const uint4*)(w2bt + head * 8192);
            for (int k = t; k < 1024; k += 256) ((uint4*)w2s)[k] = g2[k];
        }
        const float* B1 = head ? bf1 : bb1;
        const float* B2 = head ? bf2 : bb2;
        float bias1[8], bias2[4];
        #pragma unroll
        for (int c = 0; c < 8; ++c) bias1[c] = B1[c * 16 + ar];
        #pragma unroll
        for (int c = 0; c < 4; ++c) bias2[c] = B2[c * 16 + ar];
        __syncthreads();   // B3 / B5

        #pragma unroll
        for (int rt = 0; rt < 2; ++rt) {
            const int rowbase = R0 + rt * 16;
            const int yrow = rowbase + ar;
            bf16x8 ya0 = *(const bf16x8*)&ys[yrow * 64 + ((kg ^ (yrow & 7)) << 3)];
            bf16x8 ya1 = *(const bf16x8*)&ys[yrow * 64 + (((4 + kg) ^ (yrow & 7)) << 3)];
            f32x4 acc1[8];
            #pragma unroll
            for (int ct = 0; ct < 8; ++ct) acc1[ct] = (f32x4){0.f, 0.f, 0.f, 0.f};
            #pragma unroll
            for (int ct = 0; ct < 8; ++ct) {
                int brow = ct * 16 + ar;
                bf16x8 b0 = *(const bf16x8*)&w1s[brow * 64 + ((kg ^ (brow & 7)) << 3)];
                bf16x8 b1 = *(const bf16x8*)&w1s[brow * 64 + (((4 + kg) ^ (brow & 7)) << 3)];
                acc1[ct] = __builtin_amdgcn_mfma_f32_16x16x32_bf16(ya0, b0, acc1[ct], 0, 0, 0);
                acc1[ct] = __builtin_amdgcn_mfma_f32_16x16x32_bf16(ya1, b1, acc1[ct], 0, 0, 0);
            }
            #pragma unroll
            for (int ct = 0; ct < 8; ++ct) {
                #pragma unroll
                for (int r = 0; r < 4; ++r) {
                    int row = kg * 4 + r;
                    int col = ct * 16 + ar;
                    float v = fmaxf(acc1[ct][r] + bias1[ct], 0.f);
                    hw[row * 128 + (((col >> 3) ^ (row & 7)) << 3) + (col & 7)] = f2bf(v);
                }
            }
            f32x4 acc2[4];
            #pragma unroll
            for (int ct = 0; ct < 4; ++ct) acc2[ct] = (f32x4){0.f, 0.f, 0.f, 0.f};
            #pragma unroll
            for (int ks = 0; ks < 4; ++ks) {
                bf16x8 a = *(const bf16x8*)&hw[ar * 128 + (((ks * 4 + kg) ^ (ar & 7)) << 3)];
                #pragma unroll
                for (int ct = 0; ct < 4; ++ct) {
                    int brow = ct * 16 + ar;
                    bf16x8 b = *(const bf16x8*)&w2s[brow * 128 + (((ks * 4 + kg) ^ (ar & 7)) << 3)];
                    acc2[ct] = __builtin_amdgcn_mfma_f32_16x16x32_bf16(a, b, acc2[ct], 0, 0, 0);
                }
            }
            float* og = out + (size_t)head * 33554432u + (size_t)bm * 8192;
            #pragma unroll
            for (int ct = 0; ct < 4; ++ct) {
                #pragma unroll
                for (int r = 0; r < 4; ++r)
                    og[(size_t)(rowbase + kg * 4 + r) * 64 + ct * 16 + ar] =
                        acc2[ct][r] + bias2[ct];
            }
        }
        if (head == 0) __syncthreads();   // B4
    }
}

extern "C" void kernel_launch(void* const* d_in, const int* in_sizes, int n_in,
                              void* d_out, int out_size, void* d_ws, size_t ws_size,
                              hipStream_t stream)
{
    (void)in_sizes; (void)n_in; (void)out_size; (void)ws_size;
    const float* x   = (const float*)d_in[0];
    const float* ws0 = (const float*)d_in[1];
    const float* ws1 = (const float*)d_in[2];
    const float* wl  = (const float*)d_in[3];
    const float* bl  = (const float*)d_in[4];
    const float* wb1 = (const float*)d_in[5];
    const float* bb1 = (const float*)d_in[6];
    const float* wb2 = (const float*)d_in[7];
    const float* bb2 = (const float*)d_in[8];
    const float* wf1 = (const float*)d_in[9];
    const float* bf1 = (const float*)d_in[10];
    const float* wf2 = (const float*)d_in[11];
    const float* bf2 = (const float*)d_in[12];
    float* out = (float*)d_out;

    float* ws = (float*)d_ws;
    float2* w0t = (float2*)ws;                       // 131072 float2
    float2* w1t = (float2*)(ws + 262144);            // 131072 float2
    unsigned int* Tb  = (unsigned int*)(ws + 524288);    // 4194304 u32 packed
    unsigned int* Ab  = (unsigned int*)(ws + 8912896);   // 4194304 u32 packed
    float2* xft = (float2*)(ws + 17301504);          // 1048576 float2
    float2* c1b = (float2*)(ws + 19398656);          // 1048576 float2
    float2* oft = (float2*)(ws + 21495808);          // 1048576 float2
    unsigned short* w1bt    = (unsigned short*)(ws + 23592960);  // 16384 u16
    unsigned short* w2bt    = (unsigned short*)(ws + 23601152);  // 16384 u16
    unsigned short* wlt_pre = (unsigned short*)(ws + 23609344);  // 4096 u16
    unsigned short* ctb_pre = (unsigned short*)(ws + 23611392);  // 4096 u16
    unsigned short* wdft    = (unsigned short*)(ws + 23613440);  // 4352 u16

    k0_prep    <<<1024, 256, 0, stream>>>(ws0, ws1, w0t, w1t);
    k0b_prep   <<<177,  256, 0, stream>>>(wb1, wf1, wb2, wf2, wl,
                                          w1bt, w2bt, wlt_pre, ctb_pre, wdft);
    k1_dft_n   <<<4096, 256, 0, stream>>>(x, wdft, Ab);
    k2_dft_m   <<<512,  256, 0, stream>>>(Ab, xft);
    k3a_spec1  <<<1024, 256, 0, stream>>>(xft, w0t, c1b);
    k3b_spec2  <<<1024, 256, 0, stream>>>(c1b, w1t, oft);
    k4_idft_m  <<<512,  256, 0, stream>>>(oft, Tb);
    k56_fused  <<<4096, 256, 0, stream>>>(x, Tb, bl, ctb_pre, wlt_pre,
                                          w1bt, w2bt, bb1, bb2, bf1, bf2, out);
}

// Round 10
// 284.306 us; speedup vs baseline: 1.4672x; 1.0496x over previous
//
#include <hip/hip_runtime.h>
#include <hip/hip_bf16.h>

#define TWO_PI 6.28318530717958647692f

typedef __attribute__((ext_vector_type(8))) short bf16x8;
typedef __attribute__((ext_vector_type(4))) float f32x4;

__device__ __forceinline__ unsigned short f2bf(float v) {
    __hip_bfloat16 h = __float2bfloat16(v);
    return *(unsigned short*)&h;
}

__device__ __forceinline__ bf16x8 cvt8(float4 a, float4 b) {
    bf16x8 r;
    r[0] = (short)f2bf(a.x); r[1] = (short)f2bf(a.y);
    r[2] = (short)f2bf(a.z); r[3] = (short)f2bf(a.w);
    r[4] = (short)f2bf(b.x); r[5] = (short)f2bf(b.y);
    r[6] = (short)f2bf(b.z); r[7] = (short)f2bf(b.w);
    return r;
}

// Problem: B=32, M=N=128, I=O=64, NM=16.
// Spectral path keeps km in {0..15,112..127} (p=0..31), kn=0..15 (q).
// Spectral branch contributes ~1e-6 abs to y -> bf16 anywhere in it is free.
// A and T are packed bf16 pairs (u32: re low, im high).
//
// R5: MFMA operands must come from LDS/regs. R7: per-head restage regressed.
// R9: k1 as MFMA GEMM. R10: k56 processes 2 bm per block -> staging+barrier
// cost amortized 2x; LDS exactly 80K (2 blocks/CU).
//
// ws layout (float offsets):
//   w0t     @ 0        : 262144   (32 p x 64 i x 64 j complex fp32)
//   w1t     @ 262144   : 262144   (2 h x 16 kv x 64 j x 64 o complex fp32)
//   T       @ 524288   : 4194304 u32 packed bf16 (b,u,q,o)
//   A       @ 8912896  : 4194304 u32 packed bf16 (b,m,kv,i)
//   xft     @ 17301504 : 2097152 fp32
//   c1      @ 19398656 : 2097152 fp32
//   oft     @ 21495808 : 2097152 fp32
//   w1bt    @ 23592960 : 16384 u16  W1t[2][o:128][k:64] bf16 PRE-SWIZZLED
//   w2bt    @ 23601152 : 16384 u16  W2t[2][o:64][k:128] bf16 PRE-SWIZZLED
//   wlt_pre @ 23609344 : 4096 u16   w_lin^T bf16 pre-swizzled
//   ctb_pre @ 23611392 : 4096 u16   irfft coeff bf16 pre-swizzled
//   wdft    @ 23613440 : 4352 u16   DFT matrix [c:2][kv:16][n:136 pad] bf16

__global__ __launch_bounds__(256) void k0_prep(const float* __restrict__ ws0,
                                               const float* __restrict__ ws1,
                                               float2* __restrict__ w0t,
                                               float2* __restrict__ w1t)
{
    int tgt = blockIdx.x * 256 + threadIdx.x;   // 0..262143
    if (tgt < 131072) {
        int p = tgt >> 12;
        int rem = tgt & 4095;
        int i = rem >> 6, j = rem & 63;
        const float* s = (p < 16) ? ws0 : ws1;   // f=0 plane
        int px = p & 15;
        int base = ((i * 64 + j) * 16 + px) * 2;
        w0t[tgt] = make_float2(s[base], s[base + 1]);
    } else {
        int u = tgt - 131072;
        int h = u >> 16;
        int kv = (u >> 12) & 15;
        int j = (u >> 6) & 63;
        int o = u & 63;
        const float* s = (h ? ws1 : ws0) + 131072;  // f=1 plane
        int base = ((j * 64 + o) * 16 + kv) * 2;
        w1t[u] = make_float2(s[base], s[base + 1]);
    }
}

// head weights bf16 pre-swizzled + w_lin^T + irfft coeffs + DFT matrix
__global__ __launch_bounds__(256) void k0b_prep(const float* __restrict__ wb1,
                                                const float* __restrict__ wf1,
                                                const float* __restrict__ wb2,
                                                const float* __restrict__ wf2,
                                                const float* __restrict__ wl,
                                                unsigned short* __restrict__ w1bt,
                                                unsigned short* __restrict__ w2bt,
                                                unsigned short* __restrict__ wlt_pre,
                                                unsigned short* __restrict__ ctb_pre,
                                                unsigned short* __restrict__ wdft)
{
    int tgt = blockIdx.x * 256 + threadIdx.x;   // 0..45311
    if (tgt < 16384) {
        int head = tgt >> 13;
        int o = (tgt >> 6) & 127;
        int i = tgt & 63;
        const float* src = head ? wf1 : wb1;    // [64][128]
        int dst = head * 8192 + o * 64 + (((i >> 3) ^ (o & 7)) << 3) + (i & 7);
        w1bt[dst] = f2bf(src[i * 128 + o]);
    } else if (tgt < 32768) {
        int u = tgt - 16384;
        int head = u >> 13;
        int o = (u >> 7) & 63;
        int c = u & 127;
        const float* src = head ? wf2 : wb2;    // [128][64]
        int dst = head * 8192 + o * 128 + (((c >> 3) ^ (o & 7)) << 3) + (c & 7);
        w2bt[dst] = f2bf(src[c * 64 + o]);
    } else if (tgt < 36864) {
        int u = tgt - 32768;                    // 0..4095
        int o = u >> 6, i = u & 63;
        int chunk = (i >> 3) ^ (o & 7);
        wlt_pre[o * 64 + chunk * 8 + (i & 7)] = f2bf(wl[i * 64 + o]);
    } else if (tgt < 40960) {
        int u = tgt - 36864;                    // 0..4095
        int v = u >> 5, k = u & 31;             // v 0..127, k 0..31
        float val;
        if (k < 16) {
            val = (k == 0) ? (1.0f / 128.0f)
                           : (2.0f / 128.0f) * cosf(TWO_PI * k * v * (1.0f / 128.0f));
        } else {
            int q = k - 16;
            val = (q == 0) ? 0.f
                           : -(2.0f / 128.0f) * sinf(TWO_PI * q * v * (1.0f / 128.0f));
        }
        int chunk = (k >> 3) ^ ((v >> 1) & 3);
        ctb_pre[v * 32 + chunk * 8 + (k & 7)] = f2bf(val);
    } else {
        int u = tgt - 40960;                    // 0..4351
        int c = u / 2176;
        int rem = u - c * 2176;
        int kv = rem / 136, n = rem - (rem / 136) * 136;
        float val = 0.f;
        if (n < 128) {
            int idx = (kv * n) & 127;
            float th = (float)idx * (TWO_PI / 128.0f);
            val = c ? -sinf(th) : cosf(th);
        }
        wdft[u] = f2bf(val);
    }
}

// k1 (MFMA): A[b,m,kv,i] = sum_n W[kv,n] x[b,m,n,i], packed bf16 u32 out.
__global__ __launch_bounds__(256) void k1_dft_n(const float* __restrict__ x,
                                                const unsigned short* __restrict__ wdft,
                                                unsigned int* __restrict__ A)
{
    __shared__ __align__(16) unsigned short Xt[64 * 136];    // 17408 B
    __shared__ __align__(16) unsigned short Wl[2 * 16 * 136];//  8704 B
    const int t = threadIdx.x;
    const int bm = blockIdx.x;
    {   // stage DFT matrix (straight copy)
        const uint4* wg = (const uint4*)wdft;
        uint4* wl = (uint4*)Wl;
        for (int k = t; k < 544; k += 256) wl[k] = wg[k];
    }
    {   // stage x transposed
        const float* xg = x + (size_t)bm * 8192;
        const int i = t & 63, q = t >> 6;
        #pragma unroll
        for (int pass = 0; pass < 8; ++pass) {
            int n0 = pass * 16 + q * 4;
            float v0 = xg[(n0 + 0) * 64 + i];
            float v1 = xg[(n0 + 1) * 64 + i];
            float v2 = xg[(n0 + 2) * 64 + i];
            float v3 = xg[(n0 + 3) * 64 + i];
            unsigned lo = (unsigned)f2bf(v0) | ((unsigned)f2bf(v1) << 16);
            unsigned hi = (unsigned)f2bf(v2) | ((unsigned)f2bf(v3) << 16);
            *(uint2*)&Xt[i * 136 + n0] = make_uint2(lo, hi);
        }
    }
    __syncthreads();
    const int lane = t & 63, wv = t >> 6;
    const int ar = lane & 15, kg = lane >> 4;
    f32x4 are = (f32x4){0.f, 0.f, 0.f, 0.f};
    f32x4 aim = (f32x4){0.f, 0.f, 0.f, 0.f};
    #pragma unroll
    for (int ks = 0; ks < 4; ++ks) {
        int off = ks * 32 + kg * 8;
        bf16x8 b   = *(const bf16x8*)&Xt[(wv * 16 + ar) * 136 + off];
        bf16x8 wre = *(const bf16x8*)&Wl[ar * 136 + off];
        bf16x8 wim = *(const bf16x8*)&Wl[(16 + ar) * 136 + off];
        are = __builtin_amdgcn_mfma_f32_16x16x32_bf16(wre, b, are, 0, 0, 0);
        aim = __builtin_amdgcn_mfma_f32_16x16x32_bf16(wim, b, aim, 0, 0, 0);
    }
    unsigned int* Ap = A + (size_t)bm * 1024;
    #pragma unroll
    for (int r = 0; r < 4; ++r) {
        int kv = kg * 4 + r;
        int i = wv * 16 + ar;
        Ap[kv * 64 + i] = (unsigned)f2bf(are[r]) | ((unsigned)f2bf(aim[r]) << 16);
    }
}

// k2: xft[b,p,kv,i] = (1/128) sum_m A[b,m,kv,i] e^{-2pi i km(p) m/128}.
__global__ __launch_bounds__(256) void k2_dft_m(const unsigned int* __restrict__ A,
                                                float2* __restrict__ xft)
{
    __shared__ unsigned int As[128][64];
    __shared__ __align__(8) float2 tcs[128];
    const int t = threadIdx.x;
    const int b = blockIdx.x >> 4, kv = blockIdx.x & 15;
    if (t < 128) { float a = t * (TWO_PI / 128.0f); tcs[t] = make_float2(cosf(a), sinf(a)); }
    for (int k = t; k < 4096; k += 256) {
        int m = k >> 5, i2 = (k & 31) << 1;
        *(uint2*)&As[m][i2] =
            *(const uint2*)&A[((size_t)(b * 128 + m) * 16 + kv) * 64 + i2];
    }
    __syncthreads();
    const int i = t & 63;
    const int p0 = (t >> 6) << 3;
    float2 acc[8];
    #pragma unroll
    for (int j = 0; j < 8; ++j) acc[j] = make_float2(0.f, 0.f);
    for (int m = 0; m < 128; ++m) {
        unsigned pk = As[m][i];
        float ax = __uint_as_float(pk << 16);
        float ay = __uint_as_float(pk & 0xffff0000u);
        #pragma unroll
        for (int j = 0; j < 8; ++j) {
            int p = p0 + j;
            int km = (p < 16) ? p : (96 + p);
            int idx = (km * m) & 127;
            float2 cs = tcs[idx];
            acc[j].x += ax * cs.x + ay * cs.y;
            acc[j].y += ay * cs.x - ax * cs.y;
        }
    }
    const float sc = 1.0f / 128.0f;
    #pragma unroll
    for (int j = 0; j < 8; ++j)
        xft[((size_t)(b * 32 + p0 + j) * 16 + kv) * 64 + i] =
            make_float2(acc[j].x * sc, acc[j].y * sc);
}

// k3a: c1[b,p,kv,j] = sum_i xft[b,p,kv,i] * w0c[i,j,p]
__global__ __launch_bounds__(256) void k3a_spec1(const float2* __restrict__ xft,
                                                 const float2* __restrict__ w0t,
                                                 float2* __restrict__ c1)
{
    __shared__ __align__(16) float2 xs[16][64];
    __shared__ __align__(16) float2 w0s[64][64];
    const int t = threadIdx.x;
    const int b = blockIdx.x >> 5, p = blockIdx.x & 31;
    const float2* xg = xft + (size_t)(b * 32 + p) * 1024;
    for (int k = t; k < 1024; k += 256) ((float2*)xs)[k] = xg[k];
    const float4* wg = (const float4*)(w0t + (size_t)p * 4096);
    for (int k = t; k < 2048; k += 256) ((float4*)w0s)[k] = wg[k];
    __syncthreads();
    const int j = t & 63;
    const int kv0 = (t >> 6) << 2;
    float2 acc[4];
    #pragma unroll
    for (int q = 0; q < 4; ++q) acc[q] = make_float2(0.f, 0.f);
    for (int i = 0; i < 64; ++i) {
        float2 w = w0s[i][j];
        #pragma unroll
        for (int q = 0; q < 4; ++q) {
            float2 a = xs[kv0 + q][i];
            acc[q].x += a.x * w.x - a.y * w.y;
            acc[q].y += a.x * w.y + a.y * w.x;
        }
    }
    #pragma unroll
    for (int q = 0; q < 4; ++q)
        c1[((size_t)(b * 32 + p) * 16 + kv0 + q) * 64 + j] = acc[q];
}

// k3b: oft[b,p,kv,o] = sum_j c1[b,p,kv,j] * w1c[j,o,kv]
__global__ __launch_bounds__(256) void k3b_spec2(const float2* __restrict__ c1,
                                                 const float2* __restrict__ w1t,
                                                 float2* __restrict__ oft)
{
    __shared__ __align__(16) float2 cs[16][64];
    __shared__ __align__(16) float2 w1s[64][64];
    const int t = threadIdx.x;
    int id = blockIdx.x;
    const int h = id & 1; id >>= 1;
    const int kv = id & 15; const int b = id >> 4;
    for (int k = t; k < 1024; k += 256) {
        int pp = k >> 6, j = k & 63;
        cs[pp][j] = c1[((size_t)(b * 32 + h * 16 + pp) * 16 + kv) * 64 + j];
    }
    const float4* wg = (const float4*)(w1t + (size_t)(h * 16 + kv) * 4096);
    for (int k = t; k < 2048; k += 256) ((float4*)w1s)[k] = wg[k];
    __syncthreads();
    const int o = t & 63;
    const int pp0 = (t >> 6) << 2;
    float2 acc[4];
    #pragma unroll
    for (int q = 0; q < 4; ++q) acc[q] = make_float2(0.f, 0.f);
    for (int j = 0; j < 64; ++j) {
        float2 w = w1s[j][o];
        #pragma unroll
        for (int q = 0; q < 4; ++q) {
            float2 a = cs[pp0 + q][j];
            acc[q].x += a.x * w.x - a.y * w.y;
            acc[q].y += a.x * w.y + a.y * w.x;
        }
    }
    #pragma unroll
    for (int q = 0; q < 4; ++q)
        oft[((size_t)(b * 32 + h * 16 + pp0 + q) * 16 + kv) * 64 + o] = acc[q];
}

// k4: T[b,u,q,o] = sum_p oft[b,p,q,o] e^{+2pi i km(p) u/128}; packed bf16 write.
__global__ __launch_bounds__(256) void k4_idft_m(const float2* __restrict__ oft,
                                                 unsigned int* __restrict__ T)
{
    __shared__ float2 Os[32][64];
    __shared__ __align__(8) float2 tcs[128];
    const int t = threadIdx.x;
    const int b = blockIdx.x >> 4, q = blockIdx.x & 15;
    if (t < 128) { float a = t * (TWO_PI / 128.0f); tcs[t] = make_float2(cosf(a), sinf(a)); }
    for (int k = t; k < 2048; k += 256) {
        int p = k >> 6, o = k & 63;
        Os[p][o] = oft[((size_t)(b * 32 + p) * 16 + q) * 64 + o];
    }
    __syncthreads();
    const int o = t & 63;
    const int u0 = (t >> 6) << 5;
    float2 op[32];
    #pragma unroll
    for (int p = 0; p < 32; ++p) op[p] = Os[p][o];
    for (int du = 0; du < 32; ++du) {
        int u = u0 + du;
        float ax = 0.f, ay = 0.f;
        #pragma unroll
        for (int p = 0; p < 32; ++p) {
            int km = (p < 16) ? p : (96 + p);
            int idx = (km * u) & 127;
            float2 cs = tcs[idx];
            ax += op[p].x * cs.x - op[p].y * cs.y;
            ay += op[p].x * cs.y + op[p].y * cs.x;
        }
        T[((size_t)(b * 128 + u) * 16 + q) * 64 + o] =
            (unsigned)f2bf(ax) | ((unsigned)f2bf(ay) << 16);
    }
}

// k56 v6: 2 bm per block (grid 2048). LDS exactly 80K -> 2 blocks/CU.
// U (32K): phase A = Ctb 8K | wlt 8K | Tpk 8K(2bm)  ->  phase B = w1s 16K | w2s 16K.
// ys[2] 32K, hs 16K (wave-private). 5 barriers per 2-bm block.
__global__ __launch_bounds__(256) void k56_fused(
    const float* __restrict__ x, const unsigned int* __restrict__ Tg,
    const float* __restrict__ bl,
    const unsigned short* __restrict__ ctb_pre, const unsigned short* __restrict__ wlt_pre,
    const unsigned short* __restrict__ w1bt, const unsigned short* __restrict__ w2bt,
    const float* __restrict__ bb1, const float* __restrict__ bb2,
    const float* __restrict__ bf1, const float* __restrict__ bf2,
    float* __restrict__ out)
{
    __shared__ __align__(16) unsigned char U[32768];
    __shared__ __align__(16) unsigned short ys[2][8192];   // 32K
    __shared__ __align__(16) unsigned short hs[8192];      // 16K

    unsigned short* Ctb = (unsigned short*)U;              // [v:128][k:32]  8K
    unsigned short* wlt = (unsigned short*)(U + 8192);     // [o:64][k:64]   8K
    unsigned short* Tpk = (unsigned short*)(U + 16384);    // [g:2][o:64][k:32] 8K
    unsigned short* w1s = (unsigned short*)U;              // [o:128][k:64] 16K (phase B)
    unsigned short* w2s = (unsigned short*)(U + 16384);    // [o:64][k:128] 16K (phase B)

    const int t = threadIdx.x;
    const int bm0 = blockIdx.x << 1;
    const int lane = t & 63, wv = t >> 6;
    const int ar = lane & 15, kg = lane >> 4;
    const int R0 = wv * 32;

    // ---- EARLY: x loads for both bm (drain under staging + B1) ----
    float4 xr[2][2][4];
    #pragma unroll
    for (int g = 0; g < 2; ++g)
        #pragma unroll
        for (int rt = 0; rt < 2; ++rt) {
            const float* xp = x + (size_t)(bm0 + g) * 8192 + (R0 + rt * 16 + ar) * 64 + kg * 8;
            xr[g][rt][0] = *(const float4*)(xp);
            xr[g][rt][1] = *(const float4*)(xp + 4);
            xr[g][rt][2] = *(const float4*)(xp + 32);
            xr[g][rt][3] = *(const float4*)(xp + 36);
        }

    // ---- stage: Ctb/wlt straight copies; Tpk pack (2 bm) ----
    {
        const uint4* cg = (const uint4*)ctb_pre;
        for (int k = t; k < 512; k += 256) ((uint4*)Ctb)[k] = cg[k];
        const uint4* wg = (const uint4*)wlt_pre;
        for (int k = t; k < 512; k += 256) ((uint4*)wlt)[k] = wg[k];
        for (int idx = t; idx < 2048; idx += 256) {
            int g = idx >> 10, rem = idx & 1023;
            int q = rem >> 6, o = rem & 63;
            unsigned v = Tg[(size_t)(bm0 + g) * 1024 + rem];
            int f = (o >> 1) & 3;
            unsigned short* Tp = Tpk + g * 2048;
            Tp[o * 32 + (((q >> 3) ^ f) << 3) + (q & 7)] = (unsigned short)(v & 0xffffu);
            Tp[o * 32 + (((2 + (q >> 3)) ^ f) << 3) + (q & 7)] = (unsigned short)(v >> 16);
        }
    }
    __syncthreads();   // B1

    float biasl[4];
    #pragma unroll
    for (int ct = 0; ct < 4; ++ct) biasl[ct] = bl[ct * 16 + ar];

    // ---- phase A: y for both bm via MFMA ----
    #pragma unroll
    for (int g = 0; g < 2; ++g) {
        const unsigned short* Tp = Tpk + g * 2048;
        #pragma unroll
        for (int rt = 0; rt < 2; ++rt) {
            const int vrow = R0 + rt * 16 + ar;
            bf16x8 a0 = cvt8(xr[g][rt][0], xr[g][rt][1]);
            bf16x8 a1 = cvt8(xr[g][rt][2], xr[g][rt][3]);
            bf16x8 asp = *(const bf16x8*)&Ctb[vrow * 32 + ((kg ^ ((vrow >> 1) & 3)) << 3)];
            f32x4 acc[4];
            #pragma unroll
            for (int ct = 0; ct < 4; ++ct) acc[ct] = (f32x4){0.f, 0.f, 0.f, 0.f};
            #pragma unroll
            for (int ct = 0; ct < 4; ++ct) {
                int o = ct * 16 + ar;
                bf16x8 b0 = *(const bf16x8*)&wlt[o * 64 + ((kg ^ (o & 7)) << 3)];
                bf16x8 b1 = *(const bf16x8*)&wlt[o * 64 + (((4 + kg) ^ (o & 7)) << 3)];
                bf16x8 bsp = *(const bf16x8*)&Tp[o * 32 + ((kg ^ ((o >> 1) & 3)) << 3)];
                acc[ct] = __builtin_amdgcn_mfma_f32_16x16x32_bf16(a0, b0, acc[ct], 0, 0, 0);
                acc[ct] = __builtin_amdgcn_mfma_f32_16x16x32_bf16(a1, b1, acc[ct], 0, 0, 0);
                acc[ct] = __builtin_amdgcn_mfma_f32_16x16x32_bf16(asp, bsp, acc[ct], 0, 0, 0);
            }
            #pragma unroll
            for (int ct = 0; ct < 4; ++ct) {
                int col = ct * 16 + ar;
                #pragma unroll
                for (int r = 0; r < 4; ++r) {
                    int row = R0 + rt * 16 + kg * 4 + r;
                    float v = fmaxf(acc[ct][r] + biasl[ct], 0.f);
                    ys[g][row * 64 + (((col >> 3) ^ (row & 7)) << 3) + (col & 7)] = f2bf(v);
                }
            }
        }
    }
    __syncthreads();   // B2: tables dead -> U becomes w1s|w2s

    // ---- phase B: heads; weights staged once per head for BOTH bm ----
    unsigned short* hw = hs + wv * 2048;
    for (int head = 0; head < 2; ++head) {
        {
            const uint4* g1 = (const uint4*)(w1bt + head * 8192);
            for (int k = t; k < 1024; k += 256) ((uint4*)w1s)[k] = g1[k];
            const uint4* g2 = (const uint4*)(w2bt + head * 8192);
            for (int k = t; k < 1024; k += 256) ((uint4*)w2s)[k] = g2[k];
        }
        const float* B1 = head ? bf1 : bb1;
        const float* B2 = head ? bf2 : bb2;
        float bias1[8], bias2[4];
        #pragma unroll
        for (int c = 0; c < 8; ++c) bias1[c] = B1[c * 16 + ar];
        #pragma unroll
        for (int c = 0; c < 4; ++c) bias2[c] = B2[c * 16 + ar];
        __syncthreads();   // B3 / B5: weights visible

        #pragma unroll
        for (int g = 0; g < 2; ++g) {
            #pragma unroll
            for (int rt = 0; rt < 2; ++rt) {
                const int rowbase = R0 + rt * 16;
                const int yrow = rowbase + ar;
                bf16x8 ya0 = *(const bf16x8*)&ys[g][yrow * 64 + ((kg ^ (yrow & 7)) << 3)];
                bf16x8 ya1 = *(const bf16x8*)&ys[g][yrow * 64 + (((4 + kg) ^ (yrow & 7)) << 3)];
                f32x4 acc1[8];
                #pragma unroll
                for (int ct = 0; ct < 8; ++ct) acc1[ct] = (f32x4){0.f, 0.f, 0.f, 0.f};
                #pragma unroll
                for (int ct = 0; ct < 8; ++ct) {
                    int brow = ct * 16 + ar;
                    bf16x8 b0 = *(const bf16x8*)&w1s[brow * 64 + ((kg ^ (brow & 7)) << 3)];
                    bf16x8 b1 = *(const bf16x8*)&w1s[brow * 64 + (((4 + kg) ^ (brow & 7)) << 3)];
                    acc1[ct] = __builtin_amdgcn_mfma_f32_16x16x32_bf16(ya0, b0, acc1[ct], 0, 0, 0);
                    acc1[ct] = __builtin_amdgcn_mfma_f32_16x16x32_bf16(ya1, b1, acc1[ct], 0, 0, 0);
                }
                #pragma unroll
                for (int ct = 0; ct < 8; ++ct) {
                    #pragma unroll
                    for (int r = 0; r < 4; ++r) {
                        int row = kg * 4 + r;
                        int col = ct * 16 + ar;
                        float v = fmaxf(acc1[ct][r] + bias1[ct], 0.f);
                        hw[row * 128 + (((col >> 3) ^ (row & 7)) << 3) + (col & 7)] = f2bf(v);
                    }
                }
                f32x4 acc2[4];
                #pragma unroll
                for (int ct = 0; ct < 4; ++ct) acc2[ct] = (f32x4){0.f, 0.f, 0.f, 0.f};
                #pragma unroll
                for (int ks = 0; ks < 4; ++ks) {
                    bf16x8 a = *(const bf16x8*)&hw[ar * 128 + (((ks * 4 + kg) ^ (ar & 7)) << 3)];
                    #pragma unroll
                    for (int ct = 0; ct < 4; ++ct) {
                        int brow = ct * 16 + ar;
                        bf16x8 b = *(const bf16x8*)&w2s[brow * 128 + (((ks * 4 + kg) ^ (ar & 7)) << 3)];
                        acc2[ct] = __builtin_amdgcn_mfma_f32_16x16x32_bf16(a, b, acc2[ct], 0, 0, 0);
                    }
                }
                float* og = out + (size_t)head * 33554432u + (size_t)(bm0 + g) * 8192;
                #pragma unroll
                for (int ct = 0; ct < 4; ++ct) {
                    #pragma unroll
                    for (int r = 0; r < 4; ++r)
                        og[(size_t)(rowbase + kg * 4 + r) * 64 + ct * 16 + ar] =
                            acc2[ct][r] + bias2[ct];
                }
            }
        }
        if (head == 0) __syncthreads();   // B4: weight reads done before restage
    }
}

extern "C" void kernel_launch(void* const* d_in, const int* in_sizes, int n_in,
                              void* d_out, int out_size, void* d_ws, size_t ws_size,
                              hipStream_t stream)
{
    (void)in_sizes; (void)n_in; (void)out_size; (void)ws_size;
    const float* x   = (const float*)d_in[0];
    const float* ws0 = (const float*)d_in[1];
    const float* ws1 = (const float*)d_in[2];
    const float* wl  = (const float*)d_in[3];
    const float* bl  = (const float*)d_in[4];
    const float* wb1 = (const float*)d_in[5];
    const float* bb1 = (const float*)d_in[6];
    const float* wb2 = (const float*)d_in[7];
    const float* bb2 = (const float*)d_in[8];
    const float* wf1 = (const float*)d_in[9];
    const float* bf1 = (const float*)d_in[10];
    const float* wf2 = (const float*)d_in[11];
    const float* bf2 = (const float*)d_in[12];
    float* out = (float*)d_out;

    float* ws = (float*)d_ws;
    float2* w0t = (float2*)ws;                       // 131072 float2
    float2* w1t = (float2*)(ws + 262144);            // 131072 float2
    unsigned int* Tb  = (unsigned int*)(ws + 524288);    // 4194304 u32 packed
    unsigned int* Ab  = (unsigned int*)(ws + 8912896);   // 4194304 u32 packed
    float2* xft = (float2*)(ws + 17301504);          // 1048576 float2
    float2* c1b = (float2*)(ws + 19398656);          // 1048576 float2
    float2* oft = (float2*)(ws + 21495808);          // 1048576 float2
    unsigned short* w1bt    = (unsigned short*)(ws + 23592960);  // 16384 u16
    unsigned short* w2bt    = (unsigned short*)(ws + 23601152);  // 16384 u16
    unsigned short* wlt_pre = (unsigned short*)(ws + 23609344);  // 4096 u16
    unsigned short* ctb_pre = (unsigned short*)(ws + 23611392);  // 4096 u16
    unsigned short* wdft    = (unsigned short*)(ws + 23613440);  // 4352 u16

    k0_prep    <<<1024, 256, 0, stream>>>(ws0, ws1, w0t, w1t);
    k0b_prep   <<<177,  256, 0, stream>>>(wb1, wf1, wb2, wf2, wl,
                                          w1bt, w2bt, wlt_pre, ctb_pre, wdft);
    k1_dft_n   <<<4096, 256, 0, stream>>>(x, wdft, Ab);
    k2_dft_m   <<<512,  256, 0, stream>>>(Ab, xft);
    k3a_spec1  <<<1024, 256, 0, stream>>>(xft, w0t, c1b);
    k3b_spec2  <<<1024, 256, 0, stream>>>(c1b, w1t, oft);
    k4_idft_m  <<<512,  256, 0, stream>>>(oft, Tb);
    k56_fused  <<<2048, 256, 0, stream>>>(x, Tb, bl, ctb_pre, wlt_pre,
                                          w1bt, w2bt, bb1, bb2, bf1, bf2, out);
}

// Round 11
// 218.196 us; speedup vs baseline: 1.9118x; 1.3030x over previous
//
#include <hip/hip_runtime.h>
#include <hip/hip_bf16.h>

#define TWO_PI 6.28318530717958647692f

typedef __attribute__((ext_vector_type(8))) short bf16x8;
typedef __attribute__((ext_vector_type(4))) float f32x4;

__device__ __forceinline__ unsigned short f2bf(float v) {
    __hip_bfloat16 h = __float2bfloat16(v);
    return *(unsigned short*)&h;
}

__device__ __forceinline__ bf16x8 cvt8(float4 a, float4 b) {
    bf16x8 r;
    r[0] = (short)f2bf(a.x); r[1] = (short)f2bf(a.y);
    r[2] = (short)f2bf(a.z); r[3] = (short)f2bf(a.w);
    r[4] = (short)f2bf(b.x); r[5] = (short)f2bf(b.y);
    r[6] = (short)f2bf(b.z); r[7] = (short)f2bf(b.w);
    return r;
}

// Problem: B=32, M=N=128, I=O=64, NM=16.
// Spectral path keeps km in {0..15,112..127} (p=0..31), kn=0..15 (q).
// Spectral branch contributes ~1e-6 abs to y -> bf16 anywhere in it is free.
// A and T are packed bf16 pairs (u32: re low, im high).
//
// R5: MFMA operands from LDS/regs only. R9: k1 as MFMA. R10: k56 2-bm/block.
// R11: k2/k4 as MFMA via K-concat complex split:
//   k2: re=[c|s]*[ar;ai], im=[-s|c]*[ar;ai], K=256 (1/128 folded into E)
//   k4: re=[c|-s]*[re;im], im=[s|c]*[re;im], K=64
//
// ws layout (float offsets):
//   w0t     @ 0        : 262144   (32 p x 64 i x 64 j complex fp32)
//   w1t     @ 262144   : 262144   (2 h x 16 kv x 64 j x 64 o complex fp32)
//   T       @ 524288   : 4194304 u32 packed bf16 (b,u,q,o)
//   A       @ 8912896  : 4194304 u32 packed bf16 (b,m,kv,i)
//   xft     @ 17301504 : 2097152 fp32
//   c1      @ 19398656 : 2097152 fp32
//   oft     @ 21495808 : 2097152 fp32
//   w1bt    @ 23592960 : 16384 u16  W1t[2][o:128][k:64] bf16 PRE-SWIZZLED
//   w2bt    @ 23601152 : 16384 u16  W2t[2][o:64][k:128] bf16 PRE-SWIZZLED
//   wlt_pre @ 23609344 : 4096 u16   w_lin^T bf16 pre-swizzled
//   ctb_pre @ 23611392 : 4096 u16   irfft coeff bf16 pre-swizzled
//   wdft    @ 23613440 : 4352 u16   DFT matrix [c:2][kv:16][n:136 pad] bf16
//   e2k2    @ 23615616 : 16384 u16  k2 E [2][p:32][k:256] bf16 swz, 1/128 folded
//   e2k4    @ 23623808 : 16384 u16  k4 E [2][u:128][k:64] bf16 swz

__global__ __launch_bounds__(256) void k0_prep(const float* __restrict__ ws0,
                                               const float* __restrict__ ws1,
                                               float2* __restrict__ w0t,
                                               float2* __restrict__ w1t)
{
    int tgt = blockIdx.x * 256 + threadIdx.x;   // 0..262143
    if (tgt < 131072) {
        int p = tgt >> 12;
        int rem = tgt & 4095;
        int i = rem >> 6, j = rem & 63;
        const float* s = (p < 16) ? ws0 : ws1;   // f=0 plane
        int px = p & 15;
        int base = ((i * 64 + j) * 16 + px) * 2;
        w0t[tgt] = make_float2(s[base], s[base + 1]);
    } else {
        int u = tgt - 131072;
        int h = u >> 16;
        int kv = (u >> 12) & 15;
        int j = (u >> 6) & 63;
        int o = u & 63;
        const float* s = (h ? ws1 : ws0) + 131072;  // f=1 plane
        int base = ((j * 64 + o) * 16 + kv) * 2;
        w1t[u] = make_float2(s[base], s[base + 1]);
    }
}

// weights + tables (pre-swizzled where consumed from LDS)
__global__ __launch_bounds__(256) void k0b_prep(const float* __restrict__ wb1,
                                                const float* __restrict__ wf1,
                                                const float* __restrict__ wb2,
                                                const float* __restrict__ wf2,
                                                const float* __restrict__ wl,
                                                unsigned short* __restrict__ w1bt,
                                                unsigned short* __restrict__ w2bt,
                                                unsigned short* __restrict__ wlt_pre,
                                                unsigned short* __restrict__ ctb_pre,
                                                unsigned short* __restrict__ wdft,
                                                unsigned short* __restrict__ e2k2,
                                                unsigned short* __restrict__ e2k4)
{
    int tgt = blockIdx.x * 256 + threadIdx.x;   // 0..78079
    if (tgt < 16384) {
        int head = tgt >> 13;
        int o = (tgt >> 6) & 127;
        int i = tgt & 63;
        const float* src = head ? wf1 : wb1;    // [64][128]
        int dst = head * 8192 + o * 64 + (((i >> 3) ^ (o & 7)) << 3) + (i & 7);
        w1bt[dst] = f2bf(src[i * 128 + o]);
    } else if (tgt < 32768) {
        int u = tgt - 16384;
        int head = u >> 13;
        int o = (u >> 7) & 63;
        int c = u & 127;
        const float* src = head ? wf2 : wb2;    // [128][64]
        int dst = head * 8192 + o * 128 + (((c >> 3) ^ (o & 7)) << 3) + (c & 7);
        w2bt[dst] = f2bf(src[c * 64 + o]);
    } else if (tgt < 36864) {
        int u = tgt - 32768;                    // 0..4095
        int o = u >> 6, i = u & 63;
        int chunk = (i >> 3) ^ (o & 7);
        wlt_pre[o * 64 + chunk * 8 + (i & 7)] = f2bf(wl[i * 64 + o]);
    } else if (tgt < 40960) {
        int u = tgt - 36864;                    // 0..4095
        int v = u >> 5, k = u & 31;             // v 0..127, k 0..31
        float val;
        if (k < 16) {
            val = (k == 0) ? (1.0f / 128.0f)
                           : (2.0f / 128.0f) * cosf(TWO_PI * k * v * (1.0f / 128.0f));
        } else {
            int q = k - 16;
            val = (q == 0) ? 0.f
                           : -(2.0f / 128.0f) * sinf(TWO_PI * q * v * (1.0f / 128.0f));
        }
        int chunk = (k >> 3) ^ ((v >> 1) & 3);
        ctb_pre[v * 32 + chunk * 8 + (k & 7)] = f2bf(val);
    } else if (tgt < 45312) {
        int u = tgt - 40960;                    // 0..4351
        int c = u / 2176;
        int rem = u - c * 2176;
        int kv = rem / 136, n = rem - (rem / 136) * 136;
        float val = 0.f;
        if (n < 128) {
            int idx = (kv * n) & 127;
            float th = (float)idx * (TWO_PI / 128.0f);
            val = c ? -sinf(th) : cosf(th);
        }
        wdft[u] = f2bf(val);
    } else if (tgt < 61696) {
        // k2 E: [plane:2][p:32][k:256] swz; plane0=[c|s]/128, plane1=[-s|c]/128
        int u = tgt - 45312;
        int plane = u >> 13;
        int rem = u & 8191;
        int p = rem >> 8;
        int k = rem & 255;
        int km = (p < 16) ? p : (96 + p);
        int m = (k < 128) ? k : (k - 128);
        float th = (float)((km * m) & 127) * (TWO_PI / 128.0f);
        float c = cosf(th), s = sinf(th);
        float val = plane ? ((k < 128) ? -s : c) : ((k < 128) ? c : s);
        val *= (1.0f / 128.0f);
        int ch = k >> 3;
        int dst = plane * 8192 + p * 256 + (((ch & 24) | ((ch ^ p) & 7)) << 3) + (k & 7);
        e2k2[dst] = f2bf(val);
    } else {
        // k4 E: [plane:2][u:128][k:64] swz; plane0=[c|-s], plane1=[s|c]
        int u = tgt - 61696;
        int plane = u >> 13;
        int rem = u & 8191;
        int uu = rem >> 6;
        int k = rem & 63;
        int p = (k < 32) ? k : (k - 32);
        int km = (p < 16) ? p : (96 + p);
        float th = (float)((km * uu) & 127) * (TWO_PI / 128.0f);
        float c = cosf(th), s = sinf(th);
        float val = plane ? ((k < 32) ? s : c) : ((k < 32) ? c : -s);
        int ch = k >> 3;
        int dst = plane * 8192 + uu * 64 + (((ch ^ (uu & 7)) & 7) << 3) + (k & 7);
        e2k4[dst] = f2bf(val);
    }
}

// k1 (MFMA): A[b,m,kv,i] = sum_n W[kv,n] x[b,m,n,i], packed bf16 u32 out.
__global__ __launch_bounds__(256) void k1_dft_n(const float* __restrict__ x,
                                                const unsigned short* __restrict__ wdft,
                                                unsigned int* __restrict__ A)
{
    __shared__ __align__(16) unsigned short Xt[64 * 136];    // 17408 B
    __shared__ __align__(16) unsigned short Wl[2 * 16 * 136];//  8704 B
    const int t = threadIdx.x;
    const int bm = blockIdx.x;
    {
        const uint4* wg = (const uint4*)wdft;
        uint4* wl = (uint4*)Wl;
        for (int k = t; k < 544; k += 256) wl[k] = wg[k];
    }
    {
        const float* xg = x + (size_t)bm * 8192;
        const int i = t & 63, q = t >> 6;
        #pragma unroll
        for (int pass = 0; pass < 8; ++pass) {
            int n0 = pass * 16 + q * 4;
            float v0 = xg[(n0 + 0) * 64 + i];
            float v1 = xg[(n0 + 1) * 64 + i];
            float v2 = xg[(n0 + 2) * 64 + i];
            float v3 = xg[(n0 + 3) * 64 + i];
            unsigned lo = (unsigned)f2bf(v0) | ((unsigned)f2bf(v1) << 16);
            unsigned hi = (unsigned)f2bf(v2) | ((unsigned)f2bf(v3) << 16);
            *(uint2*)&Xt[i * 136 + n0] = make_uint2(lo, hi);
        }
    }
    __syncthreads();
    const int lane = t & 63, wv = t >> 6;
    const int ar = lane & 15, kg = lane >> 4;
    f32x4 are = (f32x4){0.f, 0.f, 0.f, 0.f};
    f32x4 aim = (f32x4){0.f, 0.f, 0.f, 0.f};
    #pragma unroll
    for (int ks = 0; ks < 4; ++ks) {
        int off = ks * 32 + kg * 8;
        bf16x8 b   = *(const bf16x8*)&Xt[(wv * 16 + ar) * 136 + off];
        bf16x8 wre = *(const bf16x8*)&Wl[ar * 136 + off];
        bf16x8 wim = *(const bf16x8*)&Wl[(16 + ar) * 136 + off];
        are = __builtin_amdgcn_mfma_f32_16x16x32_bf16(wre, b, are, 0, 0, 0);
        aim = __builtin_amdgcn_mfma_f32_16x16x32_bf16(wim, b, aim, 0, 0, 0);
    }
    unsigned int* Ap = A + (size_t)bm * 1024;
    #pragma unroll
    for (int r = 0; r < 4; ++r) {
        int kv = kg * 4 + r;
        int i = wv * 16 + ar;
        Ap[kv * 64 + i] = (unsigned)f2bf(are[r]) | ((unsigned)f2bf(aim[r]) << 16);
    }
}

// k2 v3 (MFMA): xft[p,i] = E*[ar;ai] per (b,kv). K=256 concat, 1/128 in E.
// LDS 64KB -> 2 blocks/CU. 32 MFMA/wave.
__global__ __launch_bounds__(256) void k2_dft_m(const unsigned int* __restrict__ A,
                                                const unsigned short* __restrict__ e2k2,
                                                float2* __restrict__ xft)
{
    __shared__ __align__(16) unsigned short El[16384];  // [2][32][256] swz, 32KB
    __shared__ __align__(16) unsigned short Sl[16384];  // [i:64][k:256] swz, 32KB
    const int t = threadIdx.x;
    const int b = blockIdx.x >> 4, kv = blockIdx.x & 15;
    {
        const uint4* eg = (const uint4*)e2k2;
        for (int k = t; k < 2048; k += 256) ((uint4*)El)[k] = eg[k];
    }
    for (int idx = t; idx < 4096; idx += 256) {
        int m2 = idx >> 6, i = idx & 63;
        int m = m2 << 1;
        unsigned a0 = A[((size_t)(b * 128 + m) * 16 + kv) * 64 + i];
        unsigned a1 = A[((size_t)(b * 128 + m + 1) * 16 + kv) * 64 + i];
        unsigned arp = (a0 & 0xffffu) | (a1 << 16);          // ar[m], ar[m+1]
        unsigned aip = (a0 >> 16) | (a1 & 0xffff0000u);      // ai[m], ai[m+1]
        int chr = m >> 3;
        *(unsigned*)&Sl[i * 256 + (((chr & 24) | ((chr ^ i) & 7)) << 3) + (m & 7)] = arp;
        int kk = 128 + m;
        int chi = kk >> 3;
        *(unsigned*)&Sl[i * 256 + (((chi & 24) | ((chi ^ i) & 7)) << 3) + (kk & 7)] = aip;
    }
    __syncthreads();
    const int lane = t & 63, wv = t >> 6;
    const int ar = lane & 15, kg = lane >> 4;
    const int pt = wv >> 1;              // p-tile (0..1)
    const int it0 = (wv & 1) << 1;       // i-tile base (0 or 2)
    #pragma unroll
    for (int iti = 0; iti < 2; ++iti) {
        int it = it0 + iti;
        int prow = pt * 16 + ar;
        int irow = it * 16 + ar;
        f32x4 accre = (f32x4){0.f, 0.f, 0.f, 0.f};
        f32x4 accim = (f32x4){0.f, 0.f, 0.f, 0.f};
        #pragma unroll
        for (int ks = 0; ks < 8; ++ks) {
            int ch = ks * 4 + kg;
            int aoff = prow * 256 + (((ch & 24) | ((ch ^ prow) & 7)) << 3);
            int boff = irow * 256 + (((ch & 24) | ((ch ^ irow) & 7)) << 3);
            bf16x8 bfrag = *(const bf16x8*)&Sl[boff];
            bf16x8 fre = *(const bf16x8*)&El[aoff];
            bf16x8 fim = *(const bf16x8*)&El[8192 + aoff];
            accre = __builtin_amdgcn_mfma_f32_16x16x32_bf16(fre, bfrag, accre, 0, 0, 0);
            accim = __builtin_amdgcn_mfma_f32_16x16x32_bf16(fim, bfrag, accim, 0, 0, 0);
        }
        #pragma unroll
        for (int r = 0; r < 4; ++r) {
            int p = pt * 16 + kg * 4 + r;
            int i = it * 16 + ar;
            xft[((size_t)(b * 32 + p) * 16 + kv) * 64 + i] =
                make_float2(accre[r], accim[r]);
        }
    }
}

// k3a: c1[b,p,kv,j] = sum_i xft[b,p,kv,i] * w0c[i,j,p]
__global__ __launch_bounds__(256) void k3a_spec1(const float2* __restrict__ xft,
                                                 const float2* __restrict__ w0t,
                                                 float2* __restrict__ c1)
{
    __shared__ __align__(16) float2 xs[16][64];
    __shared__ __align__(16) float2 w0s[64][64];
    const int t = threadIdx.x;
    const int b = blockIdx.x >> 5, p = blockIdx.x & 31;
    const float2* xg = xft + (size_t)(b * 32 + p) * 1024;
    for (int k = t; k < 1024; k += 256) ((float2*)xs)[k] = xg[k];
    const float4* wg = (const float4*)(w0t + (size_t)p * 4096);
    for (int k = t; k < 2048; k += 256) ((float4*)w0s)[k] = wg[k];
    __syncthreads();
    const int j = t & 63;
    const int kv0 = (t >> 6) << 2;
    float2 acc[4];
    #pragma unroll
    for (int q = 0; q < 4; ++q) acc[q] = make_float2(0.f, 0.f);
    for (int i = 0; i < 64; ++i) {
        float2 w = w0s[i][j];
        #pragma unroll
        for (int q = 0; q < 4; ++q) {
            float2 a = xs[kv0 + q][i];
            acc[q].x += a.x * w.x - a.y * w.y;
            acc[q].y += a.x * w.y + a.y * w.x;
        }
    }
    #pragma unroll
    for (int q = 0; q < 4; ++q)
        c1[((size_t)(b * 32 + p) * 16 + kv0 + q) * 64 + j] = acc[q];
}

// k3b: oft[b,p,kv,o] = sum_j c1[b,p,kv,j] * w1c[j,o,kv]
__global__ __launch_bounds__(256) void k3b_spec2(const float2* __restrict__ c1,
                                                 const float2* __restrict__ w1t,
                                                 float2* __restrict__ oft)
{
    __shared__ __align__(16) float2 cs[16][64];
    __shared__ __align__(16) float2 w1s[64][64];
    const int t = threadIdx.x;
    int id = blockIdx.x;
    const int h = id & 1; id >>= 1;
    const int kv = id & 15; const int b = id >> 4;
    for (int k = t; k < 1024; k += 256) {
        int pp = k >> 6, j = k & 63;
        cs[pp][j] = c1[((size_t)(b * 32 + h * 16 + pp) * 16 + kv) * 64 + j];
    }
    const float4* wg = (const float4*)(w1t + (size_t)(h * 16 + kv) * 4096);
    for (int k = t; k < 2048; k += 256) ((float4*)w1s)[k] = wg[k];
    __syncthreads();
    const int o = t & 63;
    const int pp0 = (t >> 6) << 2;
    float2 acc[4];
    #pragma unroll
    for (int q = 0; q < 4; ++q) acc[q] = make_float2(0.f, 0.f);
    for (int j = 0; j < 64; ++j) {
        float2 w = w1s[j][o];
        #pragma unroll
        for (int q = 0; q < 4; ++q) {
            float2 a = cs[pp0 + q][j];
            acc[q].x += a.x * w.x - a.y * w.y;
            acc[q].y += a.x * w.y + a.y * w.x;
        }
    }
    #pragma unroll
    for (int q = 0; q < 4; ++q)
        oft[((size_t)(b * 32 + h * 16 + pp0 + q) * 16 + kv) * 64 + o] = acc[q];
}

// k4 v2 (MFMA): T[u,o] = E*[re;im] per (b,q). K=64 concat. LDS 40KB.
__global__ __launch_bounds__(256) void k4_idft_m(const float2* __restrict__ oft,
                                                 const unsigned short* __restrict__ e2k4,
                                                 unsigned int* __restrict__ T)
{
    __shared__ __align__(16) unsigned short El[16384];  // [2][128][64] swz, 32KB
    __shared__ __align__(16) unsigned short Sl[4096];   // [o:64][k:64] swz, 8KB
    const int t = threadIdx.x;
    const int b = blockIdx.x >> 4, q = blockIdx.x & 15;
    {
        const uint4* eg = (const uint4*)e2k4;
        for (int k = t; k < 2048; k += 256) ((uint4*)El)[k] = eg[k];
    }
    for (int idx = t; idx < 1024; idx += 256) {
        int p2 = idx >> 6, o = idx & 63;
        int p = p2 << 1;
        float2 v0 = oft[((size_t)(b * 32 + p) * 16 + q) * 64 + o];
        float2 v1 = oft[((size_t)(b * 32 + p + 1) * 16 + q) * 64 + o];
        unsigned rep = (unsigned)f2bf(v0.x) | ((unsigned)f2bf(v1.x) << 16);
        unsigned imp = (unsigned)f2bf(v0.y) | ((unsigned)f2bf(v1.y) << 16);
        int chr = p >> 3;
        *(unsigned*)&Sl[o * 64 + ((chr ^ (o & 7)) << 3) + (p & 7)] = rep;
        int kk = 32 + p;
        int chi = kk >> 3;
        *(unsigned*)&Sl[o * 64 + ((chi ^ (o & 7)) << 3) + (kk & 7)] = imp;
    }
    __syncthreads();
    const int lane = t & 63, wv = t >> 6;
    const int ar = lane & 15, kg = lane >> 4;
    unsigned int* Tp = T + ((size_t)b * 128) * 1024 + (size_t)q * 64;
    #pragma unroll
    for (int uti = 0; uti < 2; ++uti) {
        int ut = wv * 2 + uti;
        int urow = ut * 16 + ar;
        int aswz = urow & 7;
        #pragma unroll
        for (int ot = 0; ot < 4; ++ot) {
            int orow = ot * 16 + ar;
            f32x4 accre = (f32x4){0.f, 0.f, 0.f, 0.f};
            f32x4 accim = (f32x4){0.f, 0.f, 0.f, 0.f};
            #pragma unroll
            for (int ks = 0; ks < 2; ++ks) {
                int ch = ks * 4 + kg;
                int aoff = urow * 64 + ((ch ^ aswz) << 3);
                int boff = orow * 64 + ((ch ^ (orow & 7)) << 3);
                bf16x8 bfrag = *(const bf16x8*)&Sl[boff];
                bf16x8 fre = *(const bf16x8*)&El[aoff];
                bf16x8 fim = *(const bf16x8*)&El[8192 + aoff];
                accre = __builtin_amdgcn_mfma_f32_16x16x32_bf16(fre, bfrag, accre, 0, 0, 0);
                accim = __builtin_amdgcn_mfma_f32_16x16x32_bf16(fim, bfrag, accim, 0, 0, 0);
            }
            #pragma unroll
            for (int r = 0; r < 4; ++r) {
                int u = ut * 16 + kg * 4 + r;
                int o = ot * 16 + ar;
                Tp[(size_t)u * 1024 + o] =
                    (unsigned)f2bf(accre[r]) | ((unsigned)f2bf(accim[r]) << 16);
            }
        }
    }
}

// k56 v6 (unchanged from R10): 2 bm per block, LDS 80K, 5 barriers.
__global__ __launch_bounds__(256) void k56_fused(
    const float* __restrict__ x, const unsigned int* __restrict__ Tg,
    const float* __restrict__ bl,
    const unsigned short* __restrict__ ctb_pre, const unsigned short* __restrict__ wlt_pre,
    const unsigned short* __restrict__ w1bt, const unsigned short* __restrict__ w2bt,
    const float* __restrict__ bb1, const float* __restrict__ bb2,
    const float* __restrict__ bf1, const float* __restrict__ bf2,
    float* __restrict__ out)
{
    __shared__ __align__(16) unsigned char U[32768];
    __shared__ __align__(16) unsigned short ys[2][8192];
    __shared__ __align__(16) unsigned short hs[8192];

    unsigned short* Ctb = (unsigned short*)U;
    unsigned short* wlt = (unsigned short*)(U + 8192);
    unsigned short* Tpk = (unsigned short*)(U + 16384);
    unsigned short* w1s = (unsigned short*)U;
    unsigned short* w2s = (unsigned short*)(U + 16384);

    const int t = threadIdx.x;
    const int bm0 = blockIdx.x << 1;
    const int lane = t & 63, wv = t >> 6;
    const int ar = lane & 15, kg = lane >> 4;
    const int R0 = wv * 32;

    float4 xr[2][2][4];
    #pragma unroll
    for (int g = 0; g < 2; ++g)
        #pragma unroll
        for (int rt = 0; rt < 2; ++rt) {
            const float* xp = x + (size_t)(bm0 + g) * 8192 + (R0 + rt * 16 + ar) * 64 + kg * 8;
            xr[g][rt][0] = *(const float4*)(xp);
            xr[g][rt][1] = *(const float4*)(xp + 4);
            xr[g][rt][2] = *(const float4*)(xp + 32);
            xr[g][rt][3] = *(const float4*)(xp + 36);
        }

    {
        const uint4* cg = (const uint4*)ctb_pre;
        for (int k = t; k < 512; k += 256) ((uint4*)Ctb)[k] = cg[k];
        const uint4* wg = (const uint4*)wlt_pre;
        for (int k = t; k < 512; k += 256) ((uint4*)wlt)[k] = wg[k];
        for (int idx = t; idx < 2048; idx += 256) {
            int g = idx >> 10, rem = idx & 1023;
            int q = rem >> 6, o = rem & 63;
            unsigned v = Tg[(size_t)(bm0 + g) * 1024 + rem];
            int f = (o >> 1) & 3;
            unsigned short* Tp = Tpk + g * 2048;
            Tp[o * 32 + (((q >> 3) ^ f) << 3) + (q & 7)] = (unsigned short)(v & 0xffffu);
            Tp[o * 32 + (((2 + (q >> 3)) ^ f) << 3) + (q & 7)] = (unsigned short)(v >> 16);
        }
    }
    __syncthreads();   // B1

    float biasl[4];
    #pragma unroll
    for (int ct = 0; ct < 4; ++ct) biasl[ct] = bl[ct * 16 + ar];

    #pragma unroll
    for (int g = 0; g < 2; ++g) {
        const unsigned short* Tp = Tpk + g * 2048;
        #pragma unroll
        for (int rt = 0; rt < 2; ++rt) {
            const int vrow = R0 + rt * 16 + ar;
            bf16x8 a0 = cvt8(xr[g][rt][0], xr[g][rt][1]);
            bf16x8 a1 = cvt8(xr[g][rt][2], xr[g][rt][3]);
            bf16x8 asp = *(const bf16x8*)&Ctb[vrow * 32 + ((kg ^ ((vrow >> 1) & 3)) << 3)];
            f32x4 acc[4];
            #pragma unroll
            for (int ct = 0; ct < 4; ++ct) acc[ct] = (f32x4){0.f, 0.f, 0.f, 0.f};
            #pragma unroll
            for (int ct = 0; ct < 4; ++ct) {
                int o = ct * 16 + ar;
                bf16x8 b0 = *(const bf16x8*)&wlt[o * 64 + ((kg ^ (o & 7)) << 3)];
                bf16x8 b1 = *(const bf16x8*)&wlt[o * 64 + (((4 + kg) ^ (o & 7)) << 3)];
                bf16x8 bsp = *(const bf16x8*)&Tp[o * 32 + ((kg ^ ((o >> 1) & 3)) << 3)];
                acc[ct] = __builtin_amdgcn_mfma_f32_16x16x32_bf16(a0, b0, acc[ct], 0, 0, 0);
                acc[ct] = __builtin_amdgcn_mfma_f32_16x16x32_bf16(a1, b1, acc[ct], 0, 0, 0);
                acc[ct] = __builtin_amdgcn_mfma_f32_16x16x32_bf16(asp, bsp, acc[ct], 0, 0, 0);
            }
            #pragma unroll
            for (int ct = 0; ct < 4; ++ct) {
                int col = ct * 16 + ar;
                #pragma unroll
                for (int r = 0; r < 4; ++r) {
                    int row = R0 + rt * 16 + kg * 4 + r;
                    float v = fmaxf(acc[ct][r] + biasl[ct], 0.f);
                    ys[g][row * 64 + (((col >> 3) ^ (row & 7)) << 3) + (col & 7)] = f2bf(v);
                }
            }
        }
    }
    __syncthreads();   // B2

    unsigned short* hw = hs + wv * 2048;
    for (int head = 0; head < 2; ++head) {
        {
            const uint4* g1 = (const uint4*)(w1bt + head * 8192);
            for (int k = t; k < 1024; k += 256) ((uint4*)w1s)[k] = g1[k];
            const uint4* g2 = (const uint4*)(w2bt + head * 8192);
            for (int k = t; k < 1024; k += 256) ((uint4*)w2s)[k] = g2[k];
        }
        const float* B1 = head ? bf1 : bb1;
        const float* B2 = head ? bf2 : bb2;
        float bias1[8], bias2[4];
        #pragma unroll
        for (int c = 0; c < 8; ++c) bias1[c] = B1[c * 16 + ar];
        #pragma unroll
        for (int c = 0; c < 4; ++c) bias2[c] = B2[c * 16 + ar];
        __syncthreads();   // B3 / B5

        #pragma unroll
        for (int g = 0; g < 2; ++g) {
            #pragma unroll
            for (int rt = 0; rt < 2; ++rt) {
                const int rowbase = R0 + rt * 16;
                const int yrow = rowbase + ar;
                bf16x8 ya0 = *(const bf16x8*)&ys[g][yrow * 64 + ((kg ^ (yrow & 7)) << 3)];
                bf16x8 ya1 = *(const bf16x8*)&ys[g][yrow * 64 + (((4 + kg) ^ (yrow & 7)) << 3)];
                f32x4 acc1[8];
                #pragma unroll
                for (int ct = 0; ct < 8; ++ct) acc1[ct] = (f32x4){0.f, 0.f, 0.f, 0.f};
                #pragma unroll
                for (int ct = 0; ct < 8; ++ct) {
                    int brow = ct * 16 + ar;
                    bf16x8 b0 = *(const bf16x8*)&w1s[brow * 64 + ((kg ^ (brow & 7)) << 3)];
                    bf16x8 b1 = *(const bf16x8*)&w1s[brow * 64 + (((4 + kg) ^ (brow & 7)) << 3)];
                    acc1[ct] = __builtin_amdgcn_mfma_f32_16x16x32_bf16(ya0, b0, acc1[ct], 0, 0, 0);
                    acc1[ct] = __builtin_amdgcn_mfma_f32_16x16x32_bf16(ya1, b1, acc1[ct], 0, 0, 0);
                }
                #pragma unroll
                for (int ct = 0; ct < 8; ++ct) {
                    #pragma unroll
                    for (int r = 0; r < 4; ++r) {
                        int row = kg * 4 + r;
                        int col = ct * 16 + ar;
                        float v = fmaxf(acc1[ct][r] + bias1[ct], 0.f);
                        hw[row * 128 + (((col >> 3) ^ (row & 7)) << 3) + (col & 7)] = f2bf(v);
                    }
                }
                f32x4 acc2[4];
                #pragma unroll
                for (int ct = 0; ct < 4; ++ct) acc2[ct] = (f32x4){0.f, 0.f, 0.f, 0.f};
                #pragma unroll
                for (int ks = 0; ks < 4; ++ks) {
                    bf16x8 a = *(const bf16x8*)&hw[ar * 128 + (((ks * 4 + kg) ^ (ar & 7)) << 3)];
                    #pragma unroll
                    for (int ct = 0; ct < 4; ++ct) {
                        int brow = ct * 16 + ar;
                        bf16x8 b = *(const bf16x8*)&w2s[brow * 128 + (((ks * 4 + kg) ^ (ar & 7)) << 3)];
                        acc2[ct] = __builtin_amdgcn_mfma_f32_16x16x32_bf16(a, b, acc2[ct], 0, 0, 0);
                    }
                }
                float* og = out + (size_t)head * 33554432u + (size_t)(bm0 + g) * 8192;
                #pragma unroll
                for (int ct = 0; ct < 4; ++ct) {
                    #pragma unroll
                    for (int r = 0; r < 4; ++r)
                        og[(size_t)(rowbase + kg * 4 + r) * 64 + ct * 16 + ar] =
                            acc2[ct][r] + bias2[ct];
                }
            }
        }
        if (head == 0) __syncthreads();   // B4
    }
}

extern "C" void kernel_launch(void* const* d_in, const int* in_sizes, int n_in,
                              void* d_out, int out_size, void* d_ws, size_t ws_size,
                              hipStream_t stream)
{
    (void)in_sizes; (void)n_in; (void)out_size; (void)ws_size;
    const float* x   = (const float*)d_in[0];
    const float* ws0 = (const float*)d_in[1];
    const float* ws1 = (const float*)d_in[2];
    const float* wl  = (const float*)d_in[3];
    const float* bl  = (const float*)d_in[4];
    const float* wb1 = (const float*)d_in[5];
    const float* bb1 = (const float*)d_in[6];
    const float* wb2 = (const float*)d_in[7];
    const float* bb2 = (const float*)d_in[8];
    const float* wf1 = (const float*)d_in[9];
    const float* bf1 = (const float*)d_in[10];
    const float* wf2 = (const float*)d_in[11];
    const float* bf2 = (const float*)d_in[12];
    float* out = (float*)d_out;

    float* ws = (float*)d_ws;
    float2* w0t = (float2*)ws;                       // 131072 float2
    float2* w1t = (float2*)(ws + 262144);            // 131072 float2
    unsigned int* Tb  = (unsigned int*)(ws + 524288);    // 4194304 u32 packed
    unsigned int* Ab  = (unsigned int*)(ws + 8912896);   // 4194304 u32 packed
    float2* xft = (float2*)(ws + 17301504);          // 1048576 float2
    float2* c1b = (float2*)(ws + 19398656);          // 1048576 float2
    float2* oft = (float2*)(ws + 21495808);          // 1048576 float2
    unsigned short* w1bt    = (unsigned short*)(ws + 23592960);  // 16384 u16
    unsigned short* w2bt    = (unsigned short*)(ws + 23601152);  // 16384 u16
    unsigned short* wlt_pre = (unsigned short*)(ws + 23609344);  // 4096 u16
    unsigned short* ctb_pre = (unsigned short*)(ws + 23611392);  // 4096 u16
    unsigned short* wdft    = (unsigned short*)(ws + 23613440);  // 4352 u16
    unsigned short* e2k2    = (unsigned short*)(ws + 23615616);  // 16384 u16
    unsigned short* e2k4    = (unsigned short*)(ws + 23623808);  // 16384 u16

    k0_prep    <<<1024, 256, 0, stream>>>(ws0, ws1, w0t, w1t);
    k0b_prep   <<<305,  256, 0, stream>>>(wb1, wf1, wb2, wf2, wl,
                                          w1bt, w2bt, wlt_pre, ctb_pre, wdft,
                                          e2k2, e2k4);
    k1_dft_n   <<<4096, 256, 0, stream>>>(x, wdft, Ab);
    k2_dft_m   <<<512,  256, 0, stream>>>(Ab, e2k2, xft);
    k3a_spec1  <<<1024, 256, 0, stream>>>(xft, w0t, c1b);
    k3b_spec2  <<<1024, 256, 0, stream>>>(c1b, w1t, oft);
    k4_idft_m  <<<512,  256, 0, stream>>>(oft, e2k4, Tb);
    k56_fused  <<<2048, 256, 0, stream>>>(x, Tb, bl, ctb_pre, wlt_pre,
                                          w1bt, w2bt, bb1, bb2, bf1, bf2, out);
}

// Round 12
// 191.344 us; speedup vs baseline: 2.1801x; 1.1403x over previous
//
#include <hip/hip_runtime.h>
#include <hip/hip_bf16.h>

#define TWO_PI 6.28318530717958647692f

typedef __attribute__((ext_vector_type(8))) short bf16x8;
typedef __attribute__((ext_vector_type(4))) float f32x4;

__device__ __forceinline__ unsigned short f2bf(float v) {
    __hip_bfloat16 h = __float2bfloat16(v);
    return *(unsigned short*)&h;
}

__device__ __forceinline__ bf16x8 cvt8(float4 a, float4 b) {
    bf16x8 r;
    r[0] = (short)f2bf(a.x); r[1] = (short)f2bf(a.y);
    r[2] = (short)f2bf(a.z); r[3] = (short)f2bf(a.w);
    r[4] = (short)f2bf(b.x); r[5] = (short)f2bf(b.y);
    r[6] = (short)f2bf(b.z); r[7] = (short)f2bf(b.w);
    return r;
}

// 128-col swizzle helper (row stride 128 u16 = 256B, ch = k>>3 in 0..15):
//   slot = ((ch&8) | ((ch^row)&7)) << 3  |  (k&7)
#define SWZ128(row, ch) ((((ch) & 8) | (((ch) ^ ((row) & 7)) & 7)) << 3)

// Problem: B=32, M=N=128, I=O=64, NM=16.
// Spectral path keeps km in {0..15,112..127} (p=0..31), kn=0..15 (q).
// Spectral branch contributes ~1e-6 abs to y -> bf16 anywhere in it is free.
// A, T, xft, c1, oft are packed bf16 pairs (u32: re low, im high).
//
// R5: MFMA operands from LDS/regs only. R9: k1 MFMA. R10: k56 2-bm/block.
// R11: k2/k4 MFMA. R12: k3a/k3b MFMA via K-concat (re=A*[wr;-wi], im=A*[wi;wr]).
//
// ws layout (float offsets):
//   w0cc    @ 0        : 524288 u16 [p:32][2][j:64][k:128] bf16 swz
//   w1cc    @ 262144   : 524288 u16 [hkv:32][2][o:64][k:128] bf16 swz
//   T       @ 524288   : 4194304 u32 packed bf16 (b,u,q,o)
//   A       @ 8912896  : 4194304 u32 packed bf16 (b,m,kv,i)
//   xft     @ 17301504 : 1048576 u32 packed (b,p,kv,i)
//   c1      @ 19398656 : 1048576 u32 packed (b,p,kv,j)
//   oft     @ 21495808 : 1048576 u32 packed (b,p,kv,o)
//   w1bt    @ 23592960 : 16384 u16  W1t[2][o:128][k:64] bf16 PRE-SWIZZLED
//   w2bt    @ 23601152 : 16384 u16  W2t[2][o:64][k:128] bf16 PRE-SWIZZLED
//   wlt_pre @ 23609344 : 4096 u16   w_lin^T bf16 pre-swizzled
//   ctb_pre @ 23611392 : 4096 u16   irfft coeff bf16 pre-swizzled
//   wdft    @ 23613440 : 4352 u16   DFT matrix [c:2][kv:16][n:136 pad] bf16
//   e2k2    @ 23615616 : 16384 u16  k2 E [2][p:32][k:256] bf16 swz, 1/128 folded
//   e2k4    @ 23623808 : 16384 u16  k4 E [2][u:128][k:64] bf16 swz

// k0: K-concat bf16 pre-swizzled spectral weights.
// w0cc plane0=[w0r | -w0i], plane1=[w0i | w0r]  (rows j, K=i-concat)
// w1cc plane0=[w1r | -w1i], plane1=[w1i | w1r]  (rows o, K=j-concat)
__global__ __launch_bounds__(256) void k0_prep(const float* __restrict__ ws0,
                                               const float* __restrict__ ws1,
                                               unsigned short* __restrict__ w0cc,
                                               unsigned short* __restrict__ w1cc)
{
    int tgt = blockIdx.x * 256 + threadIdx.x;   // 0..1048575
    int which = tgt >> 19;
    int u = tgt & 524287;
    int ps = u >> 14;          // p (w0cc) or h*16+kv (w1cc)
    int plane = (u >> 13) & 1;
    int row = (u >> 7) & 63;   // j or o
    int k = u & 127;
    int half = k >> 6, e = k & 63;
    float re, im;
    if (which == 0) {
        const float* s = (ps < 16) ? ws0 : ws1;          // f=0 plane
        int base = ((e * 64 + row) * 16 + (ps & 15)) * 2; // i=e, j=row
        re = s[base]; im = s[base + 1];
    } else {
        const float* s = ((ps >> 4) ? ws1 : ws0) + 131072; // f=1 plane
        int base = ((e * 64 + row) * 16 + (ps & 15)) * 2;  // j=e, o=row
        re = s[base]; im = s[base + 1];
    }
    float val = plane ? (half ? re : im) : (half ? -im : re);
    int ch = k >> 3;
    int dst = ps * 16384 + plane * 8192 + row * 128 + SWZ128(row, ch) + (k & 7);
    (which ? w1cc : w0cc)[dst] = f2bf(val);
}

// weights + tables (pre-swizzled where consumed from LDS)
__global__ __launch_bounds__(256) void k0b_prep(const float* __restrict__ wb1,
                                                const float* __restrict__ wf1,
                                                const float* __restrict__ wb2,
                                                const float* __restrict__ wf2,
                                                const float* __restrict__ wl,
                                                unsigned short* __restrict__ w1bt,
                                                unsigned short* __restrict__ w2bt,
                                                unsigned short* __restrict__ wlt_pre,
                                                unsigned short* __restrict__ ctb_pre,
                                                unsigned short* __restrict__ wdft,
                                                unsigned short* __restrict__ e2k2,
                                                unsigned short* __restrict__ e2k4)
{
    int tgt = blockIdx.x * 256 + threadIdx.x;   // 0..78079
    if (tgt < 16384) {
        int head = tgt >> 13;
        int o = (tgt >> 6) & 127;
        int i = tgt & 63;
        const float* src = head ? wf1 : wb1;    // [64][128]
        int dst = head * 8192 + o * 64 + (((i >> 3) ^ (o & 7)) << 3) + (i & 7);
        w1bt[dst] = f2bf(src[i * 128 + o]);
    } else if (tgt < 32768) {
        int u = tgt - 16384;
        int head = u >> 13;
        int o = (u >> 7) & 63;
        int c = u & 127;
        const float* src = head ? wf2 : wb2;    // [128][64]
        int dst = head * 8192 + o * 128 + (((c >> 3) ^ (o & 7)) << 3) + (c & 7);
        w2bt[dst] = f2bf(src[c * 64 + o]);
    } else if (tgt < 36864) {
        int u = tgt - 32768;                    // 0..4095
        int o = u >> 6, i = u & 63;
        int chunk = (i >> 3) ^ (o & 7);
        wlt_pre[o * 64 + chunk * 8 + (i & 7)] = f2bf(wl[i * 64 + o]);
    } else if (tgt < 40960) {
        int u = tgt - 36864;                    // 0..4095
        int v = u >> 5, k = u & 31;             // v 0..127, k 0..31
        float val;
        if (k < 16) {
            val = (k == 0) ? (1.0f / 128.0f)
                           : (2.0f / 128.0f) * cosf(TWO_PI * k * v * (1.0f / 128.0f));
        } else {
            int q = k - 16;
            val = (q == 0) ? 0.f
                           : -(2.0f / 128.0f) * sinf(TWO_PI * q * v * (1.0f / 128.0f));
        }
        int chunk = (k >> 3) ^ ((v >> 1) & 3);
        ctb_pre[v * 32 + chunk * 8 + (k & 7)] = f2bf(val);
    } else if (tgt < 45312) {
        int u = tgt - 40960;                    // 0..4351
        int c = u / 2176;
        int rem = u - c * 2176;
        int kv = rem / 136, n = rem - (rem / 136) * 136;
        float val = 0.f;
        if (n < 128) {
            int idx = (kv * n) & 127;
            float th = (float)idx * (TWO_PI / 128.0f);
            val = c ? -sinf(th) : cosf(th);
        }
        wdft[u] = f2bf(val);
    } else if (tgt < 61696) {
        // k2 E: [plane:2][p:32][k:256] swz; plane0=[c|s]/128, plane1=[-s|c]/128
        int u = tgt - 45312;
        int plane = u >> 13;
        int rem = u & 8191;
        int p = rem >> 8;
        int k = rem & 255;
        int km = (p < 16) ? p : (96 + p);
        int m = (k < 128) ? k : (k - 128);
        float th = (float)((km * m) & 127) * (TWO_PI / 128.0f);
        float c = cosf(th), s = sinf(th);
        float val = plane ? ((k < 128) ? -s : c) : ((k < 128) ? c : s);
        val *= (1.0f / 128.0f);
        int ch = k >> 3;
        int dst = plane * 8192 + p * 256 + (((ch & 24) | ((ch ^ p) & 7)) << 3) + (k & 7);
        e2k2[dst] = f2bf(val);
    } else {
        // k4 E: [plane:2][u:128][k:64] swz; plane0=[c|-s], plane1=[s|c]
        int u = tgt - 61696;
        int plane = u >> 13;
        int rem = u & 8191;
        int uu = rem >> 6;
        int k = rem & 63;
        int p = (k < 32) ? k : (k - 32);
        int km = (p < 16) ? p : (96 + p);
        float th = (float)((km * uu) & 127) * (TWO_PI / 128.0f);
        float c = cosf(th), s = sinf(th);
        float val = plane ? ((k < 32) ? s : c) : ((k < 32) ? c : -s);
        int ch = k >> 3;
        int dst = plane * 8192 + uu * 64 + (((ch ^ (uu & 7)) & 7) << 3) + (k & 7);
        e2k4[dst] = f2bf(val);
    }
}

// k1 (MFMA): A[b,m,kv,i] = sum_n W[kv,n] x[b,m,n,i], packed bf16 u32 out.
__global__ __launch_bounds__(256) void k1_dft_n(const float* __restrict__ x,
                                                const unsigned short* __restrict__ wdft,
                                                unsigned int* __restrict__ A)
{
    __shared__ __align__(16) unsigned short Xt[64 * 136];    // 17408 B
    __shared__ __align__(16) unsigned short Wl[2 * 16 * 136];//  8704 B
    const int t = threadIdx.x;
    const int bm = blockIdx.x;
    {
        const uint4* wg = (const uint4*)wdft;
        uint4* wl = (uint4*)Wl;
        for (int k = t; k < 544; k += 256) wl[k] = wg[k];
    }
    {
        const float* xg = x + (size_t)bm * 8192;
        const int i = t & 63, q = t >> 6;
        #pragma unroll
        for (int pass = 0; pass < 8; ++pass) {
            int n0 = pass * 16 + q * 4;
            float v0 = xg[(n0 + 0) * 64 + i];
            float v1 = xg[(n0 + 1) * 64 + i];
            float v2 = xg[(n0 + 2) * 64 + i];
            float v3 = xg[(n0 + 3) * 64 + i];
            unsigned lo = (unsigned)f2bf(v0) | ((unsigned)f2bf(v1) << 16);
            unsigned hi = (unsigned)f2bf(v2) | ((unsigned)f2bf(v3) << 16);
            *(uint2*)&Xt[i * 136 + n0] = make_uint2(lo, hi);
        }
    }
    __syncthreads();
    const int lane = t & 63, wv = t >> 6;
    const int ar = lane & 15, kg = lane >> 4;
    f32x4 are = (f32x4){0.f, 0.f, 0.f, 0.f};
    f32x4 aim = (f32x4){0.f, 0.f, 0.f, 0.f};
    #pragma unroll
    for (int ks = 0; ks < 4; ++ks) {
        int off = ks * 32 + kg * 8;
        bf16x8 b   = *(const bf16x8*)&Xt[(wv * 16 + ar) * 136 + off];
        bf16x8 wre = *(const bf16x8*)&Wl[ar * 136 + off];
        bf16x8 wim = *(const bf16x8*)&Wl[(16 + ar) * 136 + off];
        are = __builtin_amdgcn_mfma_f32_16x16x32_bf16(wre, b, are, 0, 0, 0);
        aim = __builtin_amdgcn_mfma_f32_16x16x32_bf16(wim, b, aim, 0, 0, 0);
    }
    unsigned int* Ap = A + (size_t)bm * 1024;
    #pragma unroll
    for (int r = 0; r < 4; ++r) {
        int kv = kg * 4 + r;
        int i = wv * 16 + ar;
        Ap[kv * 64 + i] = (unsigned)f2bf(are[r]) | ((unsigned)f2bf(aim[r]) << 16);
    }
}

// k2 (MFMA): xft[p,i] = E*[ar;ai] per (b,kv). K=256 concat. Packed u32 out.
__global__ __launch_bounds__(256) void k2_dft_m(const unsigned int* __restrict__ A,
                                                const unsigned short* __restrict__ e2k2,
                                                unsigned int* __restrict__ xftp)
{
    __shared__ __align__(16) unsigned short El[16384];  // [2][32][256] swz, 32KB
    __shared__ __align__(16) unsigned short Sl[16384];  // [i:64][k:256] swz, 32KB
    const int t = threadIdx.x;
    const int b = blockIdx.x >> 4, kv = blockIdx.x & 15;
    {
        const uint4* eg = (const uint4*)e2k2;
        for (int k = t; k < 2048; k += 256) ((uint4*)El)[k] = eg[k];
    }
    for (int idx = t; idx < 4096; idx += 256) {
        int m2 = idx >> 6, i = idx & 63;
        int m = m2 << 1;
        unsigned a0 = A[((size_t)(b * 128 + m) * 16 + kv) * 64 + i];
        unsigned a1 = A[((size_t)(b * 128 + m + 1) * 16 + kv) * 64 + i];
        unsigned arp = (a0 & 0xffffu) | (a1 << 16);
        unsigned aip = (a0 >> 16) | (a1 & 0xffff0000u);
        int chr = m >> 3;
        *(unsigned*)&Sl[i * 256 + (((chr & 24) | ((chr ^ i) & 7)) << 3) + (m & 7)] = arp;
        int kk = 128 + m;
        int chi = kk >> 3;
        *(unsigned*)&Sl[i * 256 + (((chi & 24) | ((chi ^ i) & 7)) << 3) + (kk & 7)] = aip;
    }
    __syncthreads();
    const int lane = t & 63, wv = t >> 6;
    const int ar = lane & 15, kg = lane >> 4;
    const int pt = wv >> 1;
    const int it0 = (wv & 1) << 1;
    #pragma unroll
    for (int iti = 0; iti < 2; ++iti) {
        int it = it0 + iti;
        int prow = pt * 16 + ar;
        int irow = it * 16 + ar;
        f32x4 accre = (f32x4){0.f, 0.f, 0.f, 0.f};
        f32x4 accim = (f32x4){0.f, 0.f, 0.f, 0.f};
        #pragma unroll
        for (int ks = 0; ks < 8; ++ks) {
            int ch = ks * 4 + kg;
            int aoff = prow * 256 + (((ch & 24) | ((ch ^ prow) & 7)) << 3);
            int boff = irow * 256 + (((ch & 24) | ((ch ^ irow) & 7)) << 3);
            bf16x8 bfrag = *(const bf16x8*)&Sl[boff];
            bf16x8 fre = *(const bf16x8*)&El[aoff];
            bf16x8 fim = *(const bf16x8*)&El[8192 + aoff];
            accre = __builtin_amdgcn_mfma_f32_16x16x32_bf16(fre, bfrag, accre, 0, 0, 0);
            accim = __builtin_amdgcn_mfma_f32_16x16x32_bf16(fim, bfrag, accim, 0, 0, 0);
        }
        #pragma unroll
        for (int r = 0; r < 4; ++r) {
            int p = pt * 16 + kg * 4 + r;
            int i = it * 16 + ar;
            xftp[((size_t)(b * 32 + p) * 16 + kv) * 64 + i] =
                (unsigned)f2bf(accre[r]) | ((unsigned)f2bf(accim[r]) << 16);
        }
    }
}

// k3a (MFMA): c1[kv,j] = xft[kv,:] @ w0cc[p] per (b,p). K=128 i-concat. 8 MFMA/wave.
__global__ __launch_bounds__(256) void k3a_spec1(const unsigned int* __restrict__ xftp,
                                                 const unsigned short* __restrict__ w0cc,
                                                 unsigned int* __restrict__ c1p)
{
    __shared__ __align__(16) unsigned short As[16 * 128];    //  4KB
    __shared__ __align__(16) unsigned short Ws[2 * 64 * 128];// 32KB
    const int t = threadIdx.x;
    const int b = blockIdx.x >> 5, p = blockIdx.x & 31;
    {
        const uint4* wg = (const uint4*)(w0cc + (size_t)p * 16384);
        for (int k = t; k < 2048; k += 256) ((uint4*)Ws)[k] = wg[k];
    }
    for (int idx = t; idx < 512; idx += 256) {
        int kvv = idx >> 5, i2 = (idx & 31) << 1;
        const unsigned* src = xftp + ((size_t)(b * 32 + p) * 16 + kvv) * 64;
        unsigned a0 = src[i2], a1 = src[i2 + 1];
        unsigned rep = (a0 & 0xffffu) | (a1 << 16);
        unsigned imp = (a0 >> 16) | (a1 & 0xffff0000u);
        int chr = i2 >> 3;
        *(unsigned*)&As[kvv * 128 + SWZ128(kvv, chr) + (i2 & 7)] = rep;
        int kk = 64 + i2;
        int chi = kk >> 3;
        *(unsigned*)&As[kvv * 128 + SWZ128(kvv, chi) + (kk & 7)] = imp;
    }
    __syncthreads();
    const int lane = t & 63, wv = t >> 6;
    const int ar = lane & 15, kg = lane >> 4;
    const int jrow = wv * 16 + ar;
    f32x4 accre = (f32x4){0.f, 0.f, 0.f, 0.f};
    f32x4 accim = (f32x4){0.f, 0.f, 0.f, 0.f};
    #pragma unroll
    for (int ks = 0; ks < 4; ++ks) {
        int ch = ks * 4 + kg;
        bf16x8 af = *(const bf16x8*)&As[ar * 128 + SWZ128(ar, ch)];
        bf16x8 br = *(const bf16x8*)&Ws[jrow * 128 + SWZ128(jrow, ch)];
        bf16x8 bi = *(const bf16x8*)&Ws[8192 + jrow * 128 + SWZ128(jrow, ch)];
        accre = __builtin_amdgcn_mfma_f32_16x16x32_bf16(af, br, accre, 0, 0, 0);
        accim = __builtin_amdgcn_mfma_f32_16x16x32_bf16(af, bi, accim, 0, 0, 0);
    }
    unsigned int* cp = c1p + ((size_t)(b * 32 + p) * 16) * 64;
    #pragma unroll
    for (int r = 0; r < 4; ++r) {
        int kv = kg * 4 + r;
        cp[kv * 64 + wv * 16 + ar] =
            (unsigned)f2bf(accre[r]) | ((unsigned)f2bf(accim[r]) << 16);
    }
}

// k3b (MFMA): oft[pp,o] = c1[pp,:] @ w1cc[h*16+kv] per (b,h,kv). K=128 j-concat.
__global__ __launch_bounds__(256) void k3b_spec2(const unsigned int* __restrict__ c1p,
                                                 const unsigned short* __restrict__ w1cc,
                                                 unsigned int* __restrict__ oftp)
{
    __shared__ __align__(16) unsigned short As[16 * 128];    //  4KB
    __shared__ __align__(16) unsigned short Ws[2 * 64 * 128];// 32KB
    const int t = threadIdx.x;
    int id = blockIdx.x;
    const int h = id & 1; id >>= 1;
    const int kv = id & 15; const int b = id >> 4;
    {
        const uint4* wg = (const uint4*)(w1cc + (size_t)(h * 16 + kv) * 16384);
        for (int k = t; k < 2048; k += 256) ((uint4*)Ws)[k] = wg[k];
    }
    for (int idx = t; idx < 512; idx += 256) {
        int pp = idx >> 5, j2 = (idx & 31) << 1;
        const unsigned* src = c1p + ((size_t)(b * 32 + h * 16 + pp) * 16 + kv) * 64;
        unsigned a0 = src[j2], a1 = src[j2 + 1];
        unsigned rep = (a0 & 0xffffu) | (a1 << 16);
        unsigned imp = (a0 >> 16) | (a1 & 0xffff0000u);
        int chr = j2 >> 3;
        *(unsigned*)&As[pp * 128 + SWZ128(pp, chr) + (j2 & 7)] = rep;
        int kk = 64 + j2;
        int chi = kk >> 3;
        *(unsigned*)&As[pp * 128 + SWZ128(pp, chi) + (kk & 7)] = imp;
    }
    __syncthreads();
    const int lane = t & 63, wv = t >> 6;
    const int ar = lane & 15, kg = lane >> 4;
    const int orow = wv * 16 + ar;
    f32x4 accre = (f32x4){0.f, 0.f, 0.f, 0.f};
    f32x4 accim = (f32x4){0.f, 0.f, 0.f, 0.f};
    #pragma unroll
    for (int ks = 0; ks < 4; ++ks) {
        int ch = ks * 4 + kg;
        bf16x8 af = *(const bf16x8*)&As[ar * 128 + SWZ128(ar, ch)];
        bf16x8 br = *(const bf16x8*)&Ws[orow * 128 + SWZ128(orow, ch)];
        bf16x8 bi = *(const bf16x8*)&Ws[8192 + orow * 128 + SWZ128(orow, ch)];
        accre = __builtin_amdgcn_mfma_f32_16x16x32_bf16(af, br, accre, 0, 0, 0);
        accim = __builtin_amdgcn_mfma_f32_16x16x32_bf16(af, bi, accim, 0, 0, 0);
    }
    #pragma unroll
    for (int r = 0; r < 4; ++r) {
        int pp = kg * 4 + r;
        oftp[((size_t)(b * 32 + h * 16 + pp) * 16 + kv) * 64 + orow] =
            (unsigned)f2bf(accre[r]) | ((unsigned)f2bf(accim[r]) << 16);
    }
}

// k4 (MFMA): T[u,o] = E*[re;im] per (b,q). K=64 concat. Packed oft in, packed T out.
__global__ __launch_bounds__(256) void k4_idft_m(const unsigned int* __restrict__ oftp,
                                                 const unsigned short* __restrict__ e2k4,
                                                 unsigned int* __restrict__ T)
{
    __shared__ __align__(16) unsigned short El[16384];  // [2][128][64] swz, 32KB
    __shared__ __align__(16) unsigned short Sl[4096];   // [o:64][k:64] swz, 8KB
    const int t = threadIdx.x;
    const int b = blockIdx.x >> 4, q = blockIdx.x & 15;
    {
        const uint4* eg = (const uint4*)e2k4;
        for (int k = t; k < 2048; k += 256) ((uint4*)El)[k] = eg[k];
    }
    for (int idx = t; idx < 1024; idx += 256) {
        int p2 = idx >> 6, o = idx & 63;
        int p = p2 << 1;
        unsigned a0 = oftp[((size_t)(b * 32 + p) * 16 + q) * 64 + o];
        unsigned a1 = oftp[((size_t)(b * 32 + p + 1) * 16 + q) * 64 + o];
        unsigned rep = (a0 & 0xffffu) | (a1 << 16);
        unsigned imp = (a0 >> 16) | (a1 & 0xffff0000u);
        int chr = p >> 3;
        *(unsigned*)&Sl[o * 64 + ((chr ^ (o & 7)) << 3) + (p & 7)] = rep;
        int kk = 32 + p;
        int chi = kk >> 3;
        *(unsigned*)&Sl[o * 64 + ((chi ^ (o & 7)) << 3) + (kk & 7)] = imp;
    }
    __syncthreads();
    const int lane = t & 63, wv = t >> 6;
    const int ar = lane & 15, kg = lane >> 4;
    unsigned int* Tp = T + ((size_t)b * 128) * 1024 + (size_t)q * 64;
    #pragma unroll
    for (int uti = 0; uti < 2; ++uti) {
        int ut = wv * 2 + uti;
        int urow = ut * 16 + ar;
        int aswz = urow & 7;
        #pragma unroll
        for (int ot = 0; ot < 4; ++ot) {
            int orow = ot * 16 + ar;
            f32x4 accre = (f32x4){0.f, 0.f, 0.f, 0.f};
            f32x4 accim = (f32x4){0.f, 0.f, 0.f, 0.f};
            #pragma unroll
            for (int ks = 0; ks < 2; ++ks) {
                int ch = ks * 4 + kg;
                int aoff = urow * 64 + ((ch ^ aswz) << 3);
                int boff = orow * 64 + ((ch ^ (orow & 7)) << 3);
                bf16x8 bfrag = *(const bf16x8*)&Sl[boff];
                bf16x8 fre = *(const bf16x8*)&El[aoff];
                bf16x8 fim = *(const bf16x8*)&El[8192 + aoff];
                accre = __builtin_amdgcn_mfma_f32_16x16x32_bf16(fre, bfrag, accre, 0, 0, 0);
                accim = __builtin_amdgcn_mfma_f32_16x16x32_bf16(fim, bfrag, accim, 0, 0, 0);
            }
            #pragma unroll
            for (int r = 0; r < 4; ++r) {
                int u = ut * 16 + kg * 4 + r;
                int o = ot * 16 + ar;
                Tp[(size_t)u * 1024 + o] =
                    (unsigned)f2bf(accre[r]) | ((unsigned)f2bf(accim[r]) << 16);
            }
        }
    }
}

// k56 (unchanged from R10): 2 bm per block, LDS 80K, 5 barriers.
__global__ __launch_bounds__(256) void k56_fused(
    const float* __restrict__ x, const unsigned int* __restrict__ Tg,
    const float* __restrict__ bl,
    const unsigned short* __restrict__ ctb_pre, const unsigned short* __restrict__ wlt_pre,
    const unsigned short* __restrict__ w1bt, const unsigned short* __restrict__ w2bt,
    const float* __restrict__ bb1, const float* __restrict__ bb2,
    const float* __restrict__ bf1, const float* __restrict__ bf2,
    float* __restrict__ out)
{
    __shared__ __align__(16) unsigned char U[32768];
    __shared__ __align__(16) unsigned short ys[2][8192];
    __shared__ __align__(16) unsigned short hs[8192];

    unsigned short* Ctb = (unsigned short*)U;
    unsigned short* wlt = (unsigned short*)(U + 8192);
    unsigned short* Tpk = (unsigned short*)(U + 16384);
    unsigned short* w1s = (unsigned short*)U;
    unsigned short* w2s = (unsigned short*)(U + 16384);

    const int t = threadIdx.x;
    const int bm0 = blockIdx.x << 1;
    const int lane = t & 63, wv = t >> 6;
    const int ar = lane & 15, kg = lane >> 4;
    const int R0 = wv * 32;

    float4 xr[2][2][4];
    #pragma unroll
    for (int g = 0; g < 2; ++g)
        #pragma unroll
        for (int rt = 0; rt < 2; ++rt) {
            const float* xp = x + (size_t)(bm0 + g) * 8192 + (R0 + rt * 16 + ar) * 64 + kg * 8;
            xr[g][rt][0] = *(const float4*)(xp);
            xr[g][rt][1] = *(const float4*)(xp + 4);
            xr[g][rt][2] = *(const float4*)(xp + 32);
            xr[g][rt][3] = *(const float4*)(xp + 36);
        }

    {
        const uint4* cg = (const uint4*)ctb_pre;
        for (int k = t; k < 512; k += 256) ((uint4*)Ctb)[k] = cg[k];
        const uint4* wg = (const uint4*)wlt_pre;
        for (int k = t; k < 512; k += 256) ((uint4*)wlt)[k] = wg[k];
        for (int idx = t; idx < 2048; idx += 256) {
            int g = idx >> 10, rem = idx & 1023;
            int q = rem >> 6, o = rem & 63;
            unsigned v = Tg[(size_t)(bm0 + g) * 1024 + rem];
            int f = (o >> 1) & 3;
            unsigned short* Tp = Tpk + g * 2048;
            Tp[o * 32 + (((q >> 3) ^ f) << 3) + (q & 7)] = (unsigned short)(v & 0xffffu);
            Tp[o * 32 + (((2 + (q >> 3)) ^ f) << 3) + (q & 7)] = (unsigned short)(v >> 16);
        }
    }
    __syncthreads();   // B1

    float biasl[4];
    #pragma unroll
    for (int ct = 0; ct < 4; ++ct) biasl[ct] = bl[ct * 16 + ar];

    #pragma unroll
    for (int g = 0; g < 2; ++g) {
        const unsigned short* Tp = Tpk + g * 2048;
        #pragma unroll
        for (int rt = 0; rt < 2; ++rt) {
            const int vrow = R0 + rt * 16 + ar;
            bf16x8 a0 = cvt8(xr[g][rt][0], xr[g][rt][1]);
            bf16x8 a1 = cvt8(xr[g][rt][2], xr[g][rt][3]);
            bf16x8 asp = *(const bf16x8*)&Ctb[vrow * 32 + ((kg ^ ((vrow >> 1) & 3)) << 3)];
            f32x4 acc[4];
            #pragma unroll
            for (int ct = 0; ct < 4; ++ct) acc[ct] = (f32x4){0.f, 0.f, 0.f, 0.f};
            #pragma unroll
            for (int ct = 0; ct < 4; ++ct) {
                int o = ct * 16 + ar;
                bf16x8 b0 = *(const bf16x8*)&wlt[o * 64 + ((kg ^ (o & 7)) << 3)];
                bf16x8 b1 = *(const bf16x8*)&wlt[o * 64 + (((4 + kg) ^ (o & 7)) << 3)];
                bf16x8 bsp = *(const bf16x8*)&Tp[o * 32 + ((kg ^ ((o >> 1) & 3)) << 3)];
                acc[ct] = __builtin_amdgcn_mfma_f32_16x16x32_bf16(a0, b0, acc[ct], 0, 0, 0);
                acc[ct] = __builtin_amdgcn_mfma_f32_16x16x32_bf16(a1, b1, acc[ct], 0, 0, 0);
                acc[ct] = __builtin_amdgcn_mfma_f32_16x16x32_bf16(asp, bsp, acc[ct], 0, 0, 0);
            }
            #pragma unroll
            for (int ct = 0; ct < 4; ++ct) {
                int col = ct * 16 + ar;
                #pragma unroll
                for (int r = 0; r < 4; ++r) {
                    int row = R0 + rt * 16 + kg * 4 + r;
                    float v = fmaxf(acc[ct][r] + biasl[ct], 0.f);
                    ys[g][row * 64 + (((col >> 3) ^ (row & 7)) << 3) + (col & 7)] = f2bf(v);
                }
            }
        }
    }
    __syncthreads();   // B2

    unsigned short* hw = hs + wv * 2048;
    for (int head = 0; head < 2; ++head) {
        {
            const uint4* g1 = (const uint4*)(w1bt + head * 8192);
            for (int k = t; k < 1024; k += 256) ((uint4*)w1s)[k] = g1[k];
            const uint4* g2 = (const uint4*)(w2bt + head * 8192);
            for (int k = t; k < 1024; k += 256) ((uint4*)w2s)[k] = g2[k];
        }
        const float* B1 = head ? bf1 : bb1;
        const float* B2 = head ? bf2 : bb2;
        float bias1[8], bias2[4];
        #pragma unroll
        for (int c = 0; c < 8; ++c) bias1[c] = B1[c * 16 + ar];
        #pragma unroll
        for (int c = 0; c < 4; ++c) bias2[c] = B2[c * 16 + ar];
        __syncthreads();   // B3 / B5

        #pragma unroll
        for (int g = 0; g < 2; ++g) {
            #pragma unroll
            for (int rt = 0; rt < 2; ++rt) {
                const int rowbase = R0 + rt * 16;
                const int yrow = rowbase + ar;
                bf16x8 ya0 = *(const bf16x8*)&ys[g][yrow * 64 + ((kg ^ (yrow & 7)) << 3)];
                bf16x8 ya1 = *(const bf16x8*)&ys[g][yrow * 64 + (((4 + kg) ^ (yrow & 7)) << 3)];
                f32x4 acc1[8];
                #pragma unroll
                for (int ct = 0; ct < 8; ++ct) acc1[ct] = (f32x4){0.f, 0.f, 0.f, 0.f};
                #pragma unroll
                for (int ct = 0; ct < 8; ++ct) {
                    int brow = ct * 16 + ar;
                    bf16x8 b0 = *(const bf16x8*)&w1s[brow * 64 + ((kg ^ (brow & 7)) << 3)];
                    bf16x8 b1 = *(const bf16x8*)&w1s[brow * 64 + (((4 + kg) ^ (brow & 7)) << 3)];
                    acc1[ct] = __builtin_amdgcn_mfma_f32_16x16x32_bf16(ya0, b0, acc1[ct], 0, 0, 0);
                    acc1[ct] = __builtin_amdgcn_mfma_f32_16x16x32_bf16(ya1, b1, acc1[ct], 0, 0, 0);
                }
                #pragma unroll
                for (int ct = 0; ct < 8; ++ct) {
                    #pragma unroll
                    for (int r = 0; r < 4; ++r) {
                        int row = kg * 4 + r;
                        int col = ct * 16 + ar;
                        float v = fmaxf(acc1[ct][r] + bias1[ct], 0.f);
                        hw[row * 128 + (((col >> 3) ^ (row & 7)) << 3) + (col & 7)] = f2bf(v);
                    }
                }
                f32x4 acc2[4];
                #pragma unroll
                for (int ct = 0; ct < 4; ++ct) acc2[ct] = (f32x4){0.f, 0.f, 0.f, 0.f};
                #pragma unroll
                for (int ks = 0; ks < 4; ++ks) {
                    bf16x8 a = *(const bf16x8*)&hw[ar * 128 + (((ks * 4 + kg) ^ (ar & 7)) << 3)];
                    #pragma unroll
                    for (int ct = 0; ct < 4; ++ct) {
                        int brow = ct * 16 + ar;
                        bf16x8 b = *(const bf16x8*)&w2s[brow * 128 + (((ks * 4 + kg) ^ (ar & 7)) << 3)];
                        acc2[ct] = __builtin_amdgcn_mfma_f32_16x16x32_bf16(a, b, acc2[ct], 0, 0, 0);
                    }
                }
                float* og = out + (size_t)head * 33554432u + (size_t)(bm0 + g) * 8192;
                #pragma unroll
                for (int ct = 0; ct < 4; ++ct) {
                    #pragma unroll
                    for (int r = 0; r < 4; ++r)
                        og[(size_t)(rowbase + kg * 4 + r) * 64 + ct * 16 + ar] =
                            acc2[ct][r] + bias2[ct];
                }
            }
        }
        if (head == 0) __syncthreads();   // B4
    }
}

extern "C" void kernel_launch(void* const* d_in, const int* in_sizes, int n_in,
                              void* d_out, int out_size, void* d_ws, size_t ws_size,
                              hipStream_t stream)
{
    (void)in_sizes; (void)n_in; (void)out_size; (void)ws_size;
    const float* x   = (const float*)d_in[0];
    const float* ws0 = (const float*)d_in[1];
    const float* ws1 = (const float*)d_in[2];
    const float* wl  = (const float*)d_in[3];
    const float* bl  = (const float*)d_in[4];
    const float* wb1 = (const float*)d_in[5];
    const float* bb1 = (const float*)d_in[6];
    const float* wb2 = (const float*)d_in[7];
    const float* bb2 = (const float*)d_in[8];
    const float* wf1 = (const float*)d_in[9];
    const float* bf1 = (const float*)d_in[10];
    const float* wf2 = (const float*)d_in[11];
    const float* bf2 = (const float*)d_in[12];
    float* out = (float*)d_out;

    float* ws = (float*)d_ws;
    unsigned short* w0cc = (unsigned short*)ws;              // 524288 u16
    unsigned short* w1cc = (unsigned short*)(ws + 262144);   // 524288 u16
    unsigned int* Tb   = (unsigned int*)(ws + 524288);       // 4194304 u32 packed
    unsigned int* Ab   = (unsigned int*)(ws + 8912896);      // 4194304 u32 packed
    unsigned int* xftp = (unsigned int*)(ws + 17301504);     // 1048576 u32 packed
    unsigned int* c1p  = (unsigned int*)(ws + 19398656);     // 1048576 u32 packed
    unsigned int* oftp = (unsigned int*)(ws + 21495808);     // 1048576 u32 packed
    unsigned short* w1bt    = (unsigned short*)(ws + 23592960);  // 16384 u16
    unsigned short* w2bt    = (unsigned short*)(ws + 23601152);  // 16384 u16
    unsigned short* wlt_pre = (unsigned short*)(ws + 23609344);  // 4096 u16
    unsigned short* ctb_pre = (unsigned short*)(ws + 23611392);  // 4096 u16
    unsigned short* wdft    = (unsigned short*)(ws + 23613440);  // 4352 u16
    unsigned short* e2k2    = (unsigned short*)(ws + 23615616);  // 16384 u16
    unsigned short* e2k4    = (unsigned short*)(ws + 23623808);  // 16384 u16

    k0_prep    <<<4096, 256, 0, stream>>>(ws0, ws1, w0cc, w1cc);
    k0b_prep   <<<305,  256, 0, stream>>>(wb1, wf1, wb2, wf2, wl,
                                          w1bt, w2bt, wlt_pre, ctb_pre, wdft,
                                          e2k2, e2k4);
    k1_dft_n   <<<4096, 256, 0, stream>>>(x, wdft, Ab);
    k2_dft_m   <<<512,  256, 0, stream>>>(Ab, e2k2, xftp);
    k3a_spec1  <<<1024, 256, 0, stream>>>(xftp, w0cc, c1p);
    k3b_spec2  <<<1024, 256, 0, stream>>>(c1p, w1cc, oftp);
    k4_idft_m  <<<512,  256, 0, stream>>>(oftp, e2k4, Tb);
    k56_fused  <<<2048, 256, 0, stream>>>(x, Tb, bl, ctb_pre, wlt_pre,
                                          w1bt, w2bt, bb1, bb2, bf1, bf2, out);
}